// Round 15
// baseline (446.051 us; speedup 1.0000x reference)
//
#include <hip/hip_runtime.h>
#include <hip/hip_fp16.h>

// ---------------- problem constants ----------------
constexpr int NV = 30000, NR = 1000;
constexpr int EVV = 400000, EVI = 120000, EIV = 120000;
constexpr int ETOT = EVV + EIV + EVI;
constexpr int VB = (NV + 3) / 4;   // veh blocks in merged gat kernels
constexpr float LOFF = 4.0f;       // logit offset (cancels in softmax ratio)

struct __align__(8) Edge { int s; __half2 ea; };
struct __align__(16) TRec { int s; int d; __half2 ea; int r; };
typedef __half2 h2;

__device__ __forceinline__ h2 h2shfl_xor(h2 v, int m) {
  int i = *(int*)&v;
  i = __shfl_xor(i, m);
  return *(h2*)&i;
}
__device__ __forceinline__ h2 h2max(h2 a, h2 b) {
  h2 r;
  asm("v_pk_max_f16 %0, %1, %2" : "=v"(r) : "v"(a), "v"(b));
  return r;
}

// ---------------- workspace layout (float units) ----------------
constexpr size_t OFF_CUR_VV = 0;                        // NV (zeroed)
constexpr size_t OFF_CUR_IV = OFF_CUR_VV + NV;          // NV (zeroed)
constexpr size_t OFF_CUR_VI = OFF_CUR_IV + NV;          // NR (zeroed)
constexpr size_t ZERO_END   = OFF_CUR_VI + NR;
constexpr size_t OFF_PTR_VV = ZERO_END;                 // NV+2
constexpr size_t OFF_PTR_IV = OFF_PTR_VV + NV + 2;
constexpr size_t OFF_PTR_VI = OFF_PTR_IV + NV + 2;
constexpr size_t OFF_E_VV   = (OFF_PTR_VI + NR + 2 + 3) & ~(size_t)3;
constexpr size_t OFF_E_IV   = OFF_E_VV + (size_t)EVV * 2;
constexpr size_t OFF_E_VI   = OFF_E_IV + (size_t)EIV * 2;
constexpr size_t OFF_TMP    = (OFF_E_VI + (size_t)EVI * 2 + 3) & ~(size_t)3;  // TRec = 4 floats
constexpr size_t OFF_H      = (OFF_TMP + (size_t)ETOT * 4 + 3) & ~(size_t)3;
// layer-1 tables: 128 halves/row = 64 float-units/row (head-interleaved: pos p = c*2+h)
constexpr size_t OFF_HL_VV1 = OFF_H;
constexpr size_t OFF_HR_VV1 = OFF_HL_VV1 + (size_t)NV * 64;
constexpr size_t OFF_HR_IV1 = OFF_HR_VV1 + (size_t)NV * 64;
constexpr size_t OFF_HL_VI1 = OFF_HR_IV1 + (size_t)NV * 64;
constexpr size_t OFF_HL_IV1 = OFF_HL_VI1 + (size_t)NV * 64;
constexpr size_t OFF_HR_VI1 = OFF_HL_IV1 + (size_t)NR * 64;
constexpr size_t L1_END     = OFF_HR_VI1 + (size_t)NR * 64;
// v1/r1: fp16 standard channel order (128 halves/row)
constexpr size_t OFF_V1     = L1_END;
constexpr size_t OFF_R1     = OFF_V1 + (size_t)NV * 64;
constexpr size_t WS_END     = OFF_R1 + (size_t)NR * 64;
// layer-2 tables overlay layer-1 region: 64 halves/row (standard order)
constexpr size_t OFF_HL_VV2 = OFF_H;
constexpr size_t OFF_HR_VV2 = OFF_HL_VV2 + (size_t)NV * 32;
constexpr size_t OFF_HR_IV2 = OFF_HR_VV2 + (size_t)NV * 32;
constexpr size_t OFF_HL_VI2 = OFF_HR_IV2 + (size_t)NV * 32;
constexpr size_t OFF_HL_IV2 = OFF_HL_VI2 + (size_t)NV * 32;
constexpr size_t OFF_HR_VI2 = OFF_HL_IV2 + (size_t)NR * 32;
constexpr size_t L2_END     = OFF_HR_VI2 + (size_t)NR * 32;
static_assert(L2_END <= OFF_V1, "layer-2 overlay must not clobber v1/r1");

// ---------------- combined layer-1 GEMM body ----------------
template<int K, int NW>
__device__ __forceinline__ void gemm1_body(float* xs, int bid,
    const float* __restrict__ X,
    const float* __restrict__ W0, const float* __restrict__ W1,
    const float* __restrict__ W2, const float* __restrict__ W3,
    __half* __restrict__ Y0, __half* __restrict__ Y1,
    __half* __restrict__ Y2, __half* __restrict__ Y3, int n) {
  constexpr int ROWS = 8;
  int r0 = bid * ROWS;
  int tid = threadIdx.x;
  int col = tid & 127, grp = tid >> 7;
  for (int i = tid; i < ROWS * K; i += 256) {
    int gi = r0 * K + i;
    xs[i] = (gi < n * K) ? X[gi] : 0.f;
  }
  __syncthreads();
  int oidx = ((col & 63) << 1) + (col >> 6);
#pragma unroll
  for (int rep = 0; rep < NW / 2; rep++) {
    int wi = grp + rep * 2;
    const float* __restrict__ W = wi == 0 ? W0 : wi == 1 ? W1 : wi == 2 ? W2 : W3;
    __half* __restrict__ Y = wi == 0 ? Y0 : wi == 1 ? Y1 : wi == 2 ? Y2 : Y3;
    float acc[ROWS];
#pragma unroll
    for (int r = 0; r < ROWS; r++) acc[r] = 0.f;
#pragma unroll
    for (int k4 = 0; k4 < K / 4; k4++) {
      float w0 = W[(4 * k4 + 0) * 128 + col];
      float w1 = W[(4 * k4 + 1) * 128 + col];
      float w2 = W[(4 * k4 + 2) * 128 + col];
      float w3 = W[(4 * k4 + 3) * 128 + col];
#pragma unroll
      for (int r = 0; r < ROWS; r++) {
        float x0 = xs[r * K + 4 * k4], x1 = xs[r * K + 4 * k4 + 1];
        float x2 = xs[r * K + 4 * k4 + 2], x3 = xs[r * K + 4 * k4 + 3];
        acc[r] = fmaf(x0, w0, acc[r]);
        acc[r] = fmaf(x1, w1, acc[r]);
        acc[r] = fmaf(x2, w2, acc[r]);
        acc[r] = fmaf(x3, w3, acc[r]);
      }
    }
#pragma unroll
    for (int r = 0; r < ROWS; r++)
      if (r0 + r < n) Y[(size_t)(r0 + r) * 128 + oidx] = __float2half(acc[r]);
  }
}

// ---------------- fused CSR-build pass-1 + layer-1 GEMM (independent; overlap) ----------------
// launch_bounds(256,8) caps VGPR at 64 so the latency-bound build blocks keep
// high occupancy; the gemm path may spill slightly (it's a small fraction).
__global__ __launch_bounds__(256, 8) void k_build1_gemm1(
    const int* __restrict__ svv, const int* __restrict__ dvv, const float* __restrict__ eavv,
    const int* __restrict__ siv, const int* __restrict__ div_, const float* __restrict__ eaiv,
    const int* __restrict__ svi, const int* __restrict__ dvi, const float* __restrict__ eavi,
    int* __restrict__ cvv, int* __restrict__ civ, int* __restrict__ cvi,
    TRec* __restrict__ tmp,
    const float* xv, const float* W0v, const float* W1v, const float* W2v, const float* W3v,
    __half* Y0v, __half* Y1v, __half* Y2v, __half* Y3v,
    const float* xr, const float* W0r, const float* W1r,
    __half* Y0r, __half* Y1r,
    int nb_build, int nbv) {
  __shared__ float xs[8 * 16];
  int bid = blockIdx.x;
  if (bid < nb_build) {
    int t = bid * 256 + threadIdx.x;
    if (t < EVV) {
      int d = dvv[t];
      float2 ea = *(const float2*)&eavv[2 * t];
      TRec rec; rec.s = svv[t]; rec.d = d;
      rec.ea = __floats2half2_rn(ea.x, ea.y);
      rec.r = atomicAdd(&cvv[d], 1);
      tmp[t] = rec;
    } else if (t < EVV + EIV) {
      int e = t - EVV, d = div_[e];
      float2 ea = *(const float2*)&eaiv[2 * e];
      TRec rec; rec.s = siv[e]; rec.d = d;
      rec.ea = __floats2half2_rn(ea.x, ea.y);
      rec.r = atomicAdd(&civ[d], 1);
      tmp[t] = rec;
    } else if (t < ETOT) {
      int e = t - EVV - EIV, d = dvi[e];
      float2 ea = *(const float2*)&eavi[2 * e];
      TRec rec; rec.s = svi[e]; rec.d = d;
      rec.ea = __floats2half2_rn(ea.x, ea.y);
      rec.r = atomicAdd(&cvi[d], 1);
      tmp[t] = rec;
    }
  } else if (bid < nb_build + nbv) {
    gemm1_body<16, 4>(xs, bid - nb_build, xv, W0v, W1v, W2v, W3v, Y0v, Y1v, Y2v, Y3v, NV);
  } else {
    gemm1_body<8, 2>(xs, bid - nb_build - nbv, xr, W0r, W1r, nullptr, nullptr,
                     Y0r, Y1r, nullptr, nullptr, NR);
  }
}

__global__ __launch_bounds__(1024) void k_scan3(
    const int* c0, int* p0, int n0,
    const int* c1, int* p1, int n1,
    const int* c2, int* p2, int n2) {
  const int* cnt = blockIdx.x == 0 ? c0 : blockIdx.x == 1 ? c1 : c2;
  int* ptr = blockIdx.x == 0 ? p0 : blockIdx.x == 1 ? p1 : p2;
  int n = blockIdx.x == 0 ? n0 : blockIdx.x == 1 ? n1 : n2;
  __shared__ int tsum[1024];
  int t = threadIdx.x;
  int per = (n + 1023) >> 10;
  int base = t * per;
  int s = 0;
  for (int i = 0; i < per; i++) { int idx = base + i; if (idx < n) s += cnt[idx]; }
  tsum[t] = s;
  for (int off = 1; off < 1024; off <<= 1) {
    __syncthreads();
    int v = (t >= off) ? tsum[t - off] : 0;
    __syncthreads();
    tsum[t] += v;
  }
  __syncthreads();
  int run = tsum[t] - s;
  for (int i = 0; i < per; i++) {
    int idx = base + i;
    if (idx < n) { ptr[idx] = run; run += cnt[idx]; }
  }
  if (t == 1023) ptr[n] = tsum[1023];
}

__global__ __launch_bounds__(256) void k_build2(
    const TRec* __restrict__ tmp,
    const int* __restrict__ pvv, const int* __restrict__ piv, const int* __restrict__ pvi,
    Edge* __restrict__ evv, Edge* __restrict__ eiv, Edge* __restrict__ evi) {
  int t = blockIdx.x * blockDim.x + threadIdx.x;
  if (t >= ETOT) return;
  TRec rec = tmp[t];
  Edge ed; ed.s = rec.s; ed.ea = rec.ea;
  if (t < EVV)            evv[pvv[rec.d] + rec.r] = ed;
  else if (t < EVV + EIV) eiv[piv[rec.d] + rec.r] = ed;
  else                    evi[pvi[rec.d] + rec.r] = ed;
}

// ---------------- combined layer-2 GEMM (veh + rsu in one launch) ----------------
template<int NW>
__device__ __forceinline__ void gemm2_body(float* xs, int bid,
    const __half* __restrict__ X,
    const float* __restrict__ W0, const float* __restrict__ W1,
    const float* __restrict__ W2, const float* __restrict__ W3,
    __half* __restrict__ Y0, __half* __restrict__ Y1,
    __half* __restrict__ Y2, __half* __restrict__ Y3, int n) {
  constexpr int ROWS = 16, K = 128;
  int r0 = bid * ROWS;
  int tid = threadIdx.x;
  const __half2* X2 = (const __half2*)X;
  for (int i = tid; i < ROWS * K / 2; i += 256) {
    int gi = r0 * (K / 2) + i;
    float2 f = (gi < n * (K / 2)) ? __half22float2(X2[gi]) : make_float2(0.f, 0.f);
    xs[2 * i] = f.x;
    xs[2 * i + 1] = f.y;
  }
  __syncthreads();
  int lane = tid & 63, wv = tid >> 6;
  if (wv >= NW) return;
  const float* __restrict__ W = wv == 0 ? W0 : wv == 1 ? W1 : wv == 2 ? W2 : W3;
  __half* __restrict__ Y = wv == 0 ? Y0 : wv == 1 ? Y1 : wv == 2 ? Y2 : Y3;
  float acc[ROWS];
#pragma unroll
  for (int r = 0; r < ROWS; r++) acc[r] = 0.f;
  for (int k4 = 0; k4 < K / 4; k4++) {
    float w0 = W[(4 * k4 + 0) * 64 + lane];
    float w1 = W[(4 * k4 + 1) * 64 + lane];
    float w2 = W[(4 * k4 + 2) * 64 + lane];
    float w3 = W[(4 * k4 + 3) * 64 + lane];
#pragma unroll
    for (int r = 0; r < ROWS; r++) {
      float x0 = xs[r * K + 4 * k4], x1 = xs[r * K + 4 * k4 + 1];
      float x2 = xs[r * K + 4 * k4 + 2], x3 = xs[r * K + 4 * k4 + 3];
      acc[r] = fmaf(x0, w0, acc[r]);
      acc[r] = fmaf(x1, w1, acc[r]);
      acc[r] = fmaf(x2, w2, acc[r]);
      acc[r] = fmaf(x3, w3, acc[r]);
    }
  }
#pragma unroll
  for (int r = 0; r < ROWS; r++)
    if (r0 + r < n) Y[(size_t)(r0 + r) * 64 + lane] = __float2half(acc[r]);
}

__global__ __launch_bounds__(256) void k_gemm2c(
    const __half* xv, const float* W0v, const float* W1v, const float* W2v, const float* W3v,
    __half* Y0v, __half* Y1v, __half* Y2v, __half* Y3v,
    const __half* xr, const float* W0r, const float* W1r,
    __half* Y0r, __half* Y1r, int nbv) {
  __shared__ float xs[16 * 128];
  if ((int)blockIdx.x < nbv)
    gemm2_body<4>(xs, blockIdx.x, xv, W0v, W1v, W2v, W3v, Y0v, Y1v, Y2v, Y3v, NV);
  else
    gemm2_body<2>(xs, blockIdx.x - nbv, xr, W0r, W1r, nullptr, nullptr,
                  Y0r, Y1r, nullptr, nullptr, NR);
}

// ---------------- window-preloaded GATv2 (pk-fp16; window0 + hr preloaded by caller) ----------------

// layer-1: H=2, head-interleaved rows, 16-lane groups; 16-chunk + 4-stride tail
template<bool SELF>
__device__ __forceinline__ void gatW2(int d, int lane, int eg, int cg,
    int b, int cnt, int es0, int eab0,
    const Edge* __restrict__ ed,
    const __half* __restrict__ hl, float4 hrr,
    const float* __restrict__ We, const float* __restrict__ att,
    float* acc, float& den0, float& den1) {
  h2 hrc2[4], av2[4], w02[4], w12[4];
  const h2* hrp = (const h2*)&hrr;
#pragma unroll
  for (int j = 0; j < 4; j++) hrc2[j] = hrp[j];
#pragma unroll
  for (int j = 0; j < 4; j++) {
    int c = cg * 4 + j;
    av2[j] = __floats2half2_rn(att[c], att[64 + c]);
    w02[j] = __floats2half2_rn(We[c], We[64 + c]);
    w12[j] = __floats2half2_rn(We[128 + c], We[192 + c]);
  }
  const h2 c02 = __float2half2_rn(0.2f);
  h2 acc2[4];
#pragma unroll
  for (int j = 0; j < 4; j++) acc2[j] = __float2half2_rn(0.f);
  float sum0 = 0.f, sum1 = 0.f;
  auto proc = [&](float4 r, int eab, bool v) {
    const h2* hp = (const h2*)&r;
    h2 eh = *(h2*)&eab;
    h2 ef0 = __low2half2(eh), ef1 = __high2half2(eh);
    h2 lacc = __float2half2_rn(0.f);
#pragma unroll
    for (int j = 0; j < 4; j++) {
      h2 g = __hfma2(ef0, w02[j], __hadd2(hp[j], hrc2[j]));
      g = __hfma2(ef1, w12[j], g);
      h2 lr = h2max(g, __hmul2(c02, g));
      lacc = __hfma2(lr, av2[j], lacc);
    }
#pragma unroll
    for (int o = 1; o <= 8; o <<= 1) lacc = __hadd2(lacc, h2shfl_xor(lacc, o));
    float2 lf = __half22float2(lacc);
    float ex0 = v ? __expf(lf.x - LOFF) : 0.f;
    float ex1 = v ? __expf(lf.y - LOFF) : 0.f;
    h2 exh = __floats2half2_rn(ex0, ex1);
#pragma unroll
    for (int j = 0; j < 4; j++) acc2[j] = __hfma2(exh, hp[j], acc2[j]);
    den0 += ex0; den1 += ex1;
  };
  auto doWin = [&](int es, int eab, int wlen) {
    int kk = 0;
    for (; kk + 16 <= wlen; kk += 16) {
      int k0 = kk + eg, k1 = kk + 4 + eg, k2 = kk + 8 + eg, k3 = kk + 12 + eg;
      int s0 = __shfl(es, k0), ea0 = __shfl(eab, k0);
      int s1 = __shfl(es, k1), ea1 = __shfl(eab, k1);
      int s2 = __shfl(es, k2), ea2 = __shfl(eab, k2);
      int s3 = __shfl(es, k3), ea3 = __shfl(eab, k3);
      float4 r0 = *(const float4*)&hl[(size_t)s0 * 128 + cg * 8];
      float4 r1 = *(const float4*)&hl[(size_t)s1 * 128 + cg * 8];
      float4 r2 = *(const float4*)&hl[(size_t)s2 * 128 + cg * 8];
      float4 r3 = *(const float4*)&hl[(size_t)s3 * 128 + cg * 8];
      proc(r0, ea0, true);
      proc(r1, ea1, true);
      proc(r2, ea2, true);
      proc(r3, ea3, true);
    }
    for (; kk < wlen; kk += 4) {
      int k0 = kk + eg;
      int s0 = __shfl(es, k0), ea0 = __shfl(eab, k0);
      float4 r0 = *(const float4*)&hl[(size_t)s0 * 128 + cg * 8];
      proc(r0, ea0, k0 < wlen);
    }
  };
  if (SELF) {
    float2 f = __half22float2(*(h2*)&eab0);
    sum0 += f.x; sum1 += f.y;
  }
  doWin(es0, eab0, min(64, cnt));
  for (int wf = 64; wf < cnt; wf += 64) {
    int idx = wf + lane;
    int es = 0, eab = 0;
    if (idx < cnt) { Edge e = ed[b + idx]; es = e.s; eab = *(const int*)&e.ea; }
    if (SELF) {
      float2 f = __half22float2(*(h2*)&eab);
      sum0 += f.x; sum1 += f.y;
    }
    doWin(es, eab, min(64, cnt - wf));
  }
  if (SELF) {
#pragma unroll
    for (int o = 1; o <= 32; o <<= 1) { sum0 += __shfl_xor(sum0, o); sum1 += __shfl_xor(sum1, o); }
    float dg = fmaxf((float)cnt, 1.f);
    __half2 mh = __floats2half2_rn(sum0 / dg, sum1 / dg);
    int meab = *(const int*)&mh;
    float4 rS = *(const float4*)&hl[(size_t)d * 128 + cg * 8];
    proc(rS, meab, eg == 0);
  }
#pragma unroll
  for (int o = 16; o <= 32; o <<= 1) {
#pragma unroll
    for (int j = 0; j < 4; j++) acc2[j] = __hadd2(acc2[j], h2shfl_xor(acc2[j], o));
    den0 += __shfl_xor(den0, o);
    den1 += __shfl_xor(den1, o);
  }
#pragma unroll
  for (int j = 0; j < 4; j++) {
    float2 f = __half22float2(acc2[j]);
    acc[2 * j] = f.x; acc[2 * j + 1] = f.y;
  }
}

// layer-2: H=1, standard rows, 8-lane groups; 32-chunk + 8-stride tail
template<bool SELF>
__device__ __forceinline__ void gatW1(int d, int lane, int eg8, int cg8,
    int b, int cnt, int es0, int eab0,
    const Edge* __restrict__ ed,
    const __half* __restrict__ hl, float4 hrr,
    const float* __restrict__ We, const float* __restrict__ att,
    float* acc, float& den) {
  h2 hrc2[4], av2[4], w02[4], w12[4];
  const h2* hrp = (const h2*)&hrr;
#pragma unroll
  for (int j = 0; j < 4; j++) hrc2[j] = hrp[j];
#pragma unroll
  for (int j = 0; j < 4; j++) {
    int c = cg8 * 8 + 2 * j;
    av2[j] = __floats2half2_rn(att[c], att[c + 1]);
    w02[j] = __floats2half2_rn(We[c], We[c + 1]);
    w12[j] = __floats2half2_rn(We[64 + c], We[64 + c + 1]);
  }
  const h2 c02 = __float2half2_rn(0.2f);
  h2 acc2[4];
#pragma unroll
  for (int j = 0; j < 4; j++) acc2[j] = __float2half2_rn(0.f);
  float sum0 = 0.f, sum1 = 0.f;
  auto proc = [&](float4 r, int eab, bool v) {
    const h2* hp = (const h2*)&r;
    h2 eh = *(h2*)&eab;
    h2 ef0 = __low2half2(eh), ef1 = __high2half2(eh);
    h2 lacc = __float2half2_rn(0.f);
#pragma unroll
    for (int j = 0; j < 4; j++) {
      h2 g = __hfma2(ef0, w02[j], __hadd2(hp[j], hrc2[j]));
      g = __hfma2(ef1, w12[j], g);
      h2 lr = h2max(g, __hmul2(c02, g));
      lacc = __hfma2(lr, av2[j], lacc);
    }
#pragma unroll
    for (int o = 1; o <= 4; o <<= 1) lacc = __hadd2(lacc, h2shfl_xor(lacc, o));
    float2 lf = __half22float2(lacc);
    float ex = v ? __expf(lf.x + lf.y - LOFF) : 0.f;
    h2 exh = __float2half2_rn(ex);
#pragma unroll
    for (int j = 0; j < 4; j++) acc2[j] = __hfma2(exh, hp[j], acc2[j]);
    den += ex;
  };
  auto doWin = [&](int es, int eab, int wlen) {
    int kk = 0;
    for (; kk + 32 <= wlen; kk += 32) {
      int k0 = kk + eg8, k1 = kk + 8 + eg8, k2 = kk + 16 + eg8, k3 = kk + 24 + eg8;
      int s0 = __shfl(es, k0), ea0 = __shfl(eab, k0);
      int s1 = __shfl(es, k1), ea1 = __shfl(eab, k1);
      int s2 = __shfl(es, k2), ea2 = __shfl(eab, k2);
      int s3 = __shfl(es, k3), ea3 = __shfl(eab, k3);
      float4 r0 = *(const float4*)&hl[(size_t)s0 * 64 + cg8 * 8];
      float4 r1 = *(const float4*)&hl[(size_t)s1 * 64 + cg8 * 8];
      float4 r2 = *(const float4*)&hl[(size_t)s2 * 64 + cg8 * 8];
      float4 r3 = *(const float4*)&hl[(size_t)s3 * 64 + cg8 * 8];
      proc(r0, ea0, true);
      proc(r1, ea1, true);
      proc(r2, ea2, true);
      proc(r3, ea3, true);
    }
    for (; kk < wlen; kk += 8) {
      int k0 = kk + eg8;
      int s0 = __shfl(es, k0), ea0 = __shfl(eab, k0);
      float4 r0 = *(const float4*)&hl[(size_t)s0 * 64 + cg8 * 8];
      proc(r0, ea0, k0 < wlen);
    }
  };
  if (SELF) {
    float2 f = __half22float2(*(h2*)&eab0);
    sum0 += f.x; sum1 += f.y;
  }
  doWin(es0, eab0, min(64, cnt));
  for (int wf = 64; wf < cnt; wf += 64) {
    int idx = wf + lane;
    int es = 0, eab = 0;
    if (idx < cnt) { Edge e = ed[b + idx]; es = e.s; eab = *(const int*)&e.ea; }
    if (SELF) {
      float2 f = __half22float2(*(h2*)&eab);
      sum0 += f.x; sum1 += f.y;
    }
    doWin(es, eab, min(64, cnt - wf));
  }
  if (SELF) {
#pragma unroll
    for (int o = 1; o <= 32; o <<= 1) { sum0 += __shfl_xor(sum0, o); sum1 += __shfl_xor(sum1, o); }
    float dg = fmaxf((float)cnt, 1.f);
    __half2 mh = __floats2half2_rn(sum0 / dg, sum1 / dg);
    int meab = *(const int*)&mh;
    float4 rS = *(const float4*)&hl[(size_t)d * 64 + cg8 * 8];
    proc(rS, meab, eg8 == 0);
  }
#pragma unroll
  for (int o = 8; o <= 32; o <<= 1) {
#pragma unroll
    for (int j = 0; j < 4; j++) acc2[j] = __hadd2(acc2[j], h2shfl_xor(acc2[j], o));
    den += __shfl_xor(den, o);
  }
#pragma unroll
  for (int j = 0; j < 4; j++) {
    float2 f = __half22float2(acc2[j]);
    acc[2 * j] = f.x; acc[2 * j + 1] = f.y;
  }
}

// layer-1 merged: blocks [0,NR) = rsu (block/dst), [NR,NR+VB) = veh (wave/dst)
__global__ __launch_bounds__(256) void k_gat_l1(
    const int* ptr_vv, const Edge* e_vv,
    const __half* hl_vv, const __half* hr_vv, const float* We_vv, const float* att_vv,
    const int* ptr_iv, const Edge* e_iv,
    const __half* hl_iv, const __half* hr_iv, const float* We_iv, const float* att_iv,
    const int* ptr_vi, const Edge* e_vi,
    const __half* hl_vi, const __half* hr_vi, const float* We_vi, const float* att_vi,
    const float* b_vv, const float* b_iv, const float* b_vi,
    __half* __restrict__ v1, __half* __restrict__ r1) {
  __shared__ float sm[4][16][10];
  int lane = threadIdx.x & 63, wv = threadIdx.x >> 6;
  int eg = lane >> 4, cg = lane & 15;
  if (blockIdx.x >= NR) {
    int w = (blockIdx.x - NR) * 4 + wv;
    if (w >= NV) return;
    int b1 = ptr_vv[w], c1 = ptr_vv[w + 1] - b1;
    int b2 = ptr_iv[w], c2 = ptr_iv[w + 1] - b2;
    int es1 = 0, ea1 = 0, es2 = 0, ea2 = 0;
    if (lane < c1) { Edge e = e_vv[b1 + lane]; es1 = e.s; ea1 = *(const int*)&e.ea; }
    if (lane < c2) { Edge e = e_iv[b2 + lane]; es2 = e.s; ea2 = *(const int*)&e.ea; }
    float4 hrv = *(const float4*)&hr_vv[(size_t)w * 128 + cg * 8];
    float4 hri = *(const float4*)&hr_iv[(size_t)w * 128 + cg * 8];
    float acc[8];
    float d0 = 0.f, d1 = 0.f, oc[8];
    gatW2<true>(w, lane, eg, cg, b1, c1, es1, ea1, e_vv, hl_vv, hrv, We_vv, att_vv, acc, d0, d1);
#pragma unroll
    for (int j = 0; j < 8; j++) oc[j] = acc[j] / (((j & 1) ? d1 : d0) + 1e-16f);
    d0 = d1 = 0.f;
    gatW2<false>(w, lane, eg, cg, b2, c2, es2, ea2, e_iv, hl_iv, hri, We_iv, att_iv, acc, d0, d1);
#pragma unroll
    for (int j = 0; j < 8; j++) oc[j] += acc[j] / (((j & 1) ? d1 : d0) + 1e-16f);
    if (eg == 0) {
      float x[8];
#pragma unroll
      for (int j = 0; j < 8; j++) {
        int c = cg * 4 + (j >> 1);
        int idx = (j & 1) * 64 + c;
        float v = oc[j] + b_vv[idx] + b_iv[idx];
        x[j] = v > 0.f ? v : __expf(v) - 1.f;
      }
      __half2 h0a = __floats2half2_rn(x[0], x[2]), h0b = __floats2half2_rn(x[4], x[6]);
      __half2 h1a = __floats2half2_rn(x[1], x[3]), h1b = __floats2half2_rn(x[5], x[7]);
      float2 p0, p1;
      ((__half2*)&p0)[0] = h0a; ((__half2*)&p0)[1] = h0b;
      ((__half2*)&p1)[0] = h1a; ((__half2*)&p1)[1] = h1b;
      *(float2*)&v1[(size_t)w * 128 + cg * 4]      = p0;
      *(float2*)&v1[(size_t)w * 128 + 64 + cg * 4] = p1;
    }
  } else {
    int dd = blockIdx.x;
    int bfull = ptr_vi[dd], cntf = ptr_vi[dd + 1] - bfull;
    int q = (cntf + 3) >> 2;
    int off = min(wv * q, cntf);
    int cnt = min(q, cntf - off);
    int b = bfull + off;
    int es0 = 0, ea0 = 0;
    if (lane < cnt) { Edge e = e_vi[b + lane]; es0 = e.s; ea0 = *(const int*)&e.ea; }
    float4 hrr = *(const float4*)&hr_vi[(size_t)dd * 128 + cg * 8];
    float acc[8];
    float d0 = 0.f, d1 = 0.f;
    gatW2<false>(dd, lane, eg, cg, b, cnt, es0, ea0, e_vi, hl_vi, hrr, We_vi, att_vi, acc, d0, d1);
    if (eg == 0) {
#pragma unroll
      for (int j = 0; j < 8; j++) sm[wv][cg][j] = acc[j];
      sm[wv][cg][8] = d0; sm[wv][cg][9] = d1;
    }
    __syncthreads();
    if (wv == 0) {
#pragma unroll
      for (int j = 0; j < 8; j++)
        acc[j] = sm[0][cg][j] + sm[1][cg][j] + sm[2][cg][j] + sm[3][cg][j];
      d0 = sm[0][cg][8] + sm[1][cg][8] + sm[2][cg][8] + sm[3][cg][8];
      d1 = sm[0][cg][9] + sm[1][cg][9] + sm[2][cg][9] + sm[3][cg][9];
      if (eg == 0) {
        float x[8];
#pragma unroll
        for (int j = 0; j < 8; j++) {
          int c = cg * 4 + (j >> 1);
          int idx = (j & 1) * 64 + c;
          float v = acc[j] / (((j & 1) ? d1 : d0) + 1e-16f) + b_vi[idx];
          x[j] = v > 0.f ? v : __expf(v) - 1.f;
        }
        __half2 h0a = __floats2half2_rn(x[0], x[2]), h0b = __floats2half2_rn(x[4], x[6]);
        __half2 h1a = __floats2half2_rn(x[1], x[3]), h1b = __floats2half2_rn(x[5], x[7]);
        float2 p0, p1;
        ((__half2*)&p0)[0] = h0a; ((__half2*)&p0)[1] = h0b;
        ((__half2*)&p1)[0] = h1a; ((__half2*)&p1)[1] = h1b;
        *(float2*)&r1[(size_t)dd * 128 + cg * 4]      = p0;
        *(float2*)&r1[(size_t)dd * 128 + 64 + cg * 4] = p1;
      }
    }
  }
}

// layer-2 merged: rsu blocks first; veh rows -> out[0..NV), rsu -> out[NV..)
__global__ __launch_bounds__(256) void k_gat_l2(
    const int* ptr_vv, const Edge* e_vv,
    const __half* hl_vv, const __half* hr_vv, const float* We_vv, const float* att_vv,
    const int* ptr_iv, const Edge* e_iv,
    const __half* hl_iv, const __half* hr_iv, const float* We_iv, const float* att_iv,
    const int* ptr_vi, const Edge* e_vi,
    const __half* hl_vi, const __half* hr_vi, const float* We_vi, const float* att_vi,
    const float* b_vv, const float* b_iv, const float* b_vi,
    const float* ln_vg, const float* ln_vb, const float* ln_rg, const float* ln_rb,
    float* __restrict__ out) {
  __shared__ float sm[4][8][9];
  int lane = threadIdx.x & 63, wv = threadIdx.x >> 6;
  int eg8 = lane >> 3, cg8 = lane & 7;
  if (blockIdx.x >= NR) {
    int w = (blockIdx.x - NR) * 4 + wv;
    if (w >= NV) return;
    int b1 = ptr_vv[w], c1 = ptr_vv[w + 1] - b1;
    int b2 = ptr_iv[w], c2 = ptr_iv[w + 1] - b2;
    int es1 = 0, ea1 = 0, es2 = 0, ea2 = 0;
    if (lane < c1) { Edge e = e_vv[b1 + lane]; es1 = e.s; ea1 = *(const int*)&e.ea; }
    if (lane < c2) { Edge e = e_iv[b2 + lane]; es2 = e.s; ea2 = *(const int*)&e.ea; }
    float4 hrv = *(const float4*)&hr_vv[(size_t)w * 64 + cg8 * 8];
    float4 hri = *(const float4*)&hr_iv[(size_t)w * 64 + cg8 * 8];
    float acc[8];
    float dn = 0.f, oc[8];
    gatW1<true>(w, lane, eg8, cg8, b1, c1, es1, ea1, e_vv, hl_vv, hrv, We_vv, att_vv, acc, dn);
#pragma unroll
    for (int j = 0; j < 8; j++) oc[j] = acc[j] / (dn + 1e-16f);
    dn = 0.f;
    gatW1<false>(w, lane, eg8, cg8, b2, c2, es2, ea2, e_iv, hl_iv, hri, We_iv, att_iv, acc, dn);
    float x[8], s = 0.f;
#pragma unroll
    for (int j = 0; j < 8; j++) {
      int c = cg8 * 8 + j;
      x[j] = oc[j] + acc[j] / (dn + 1e-16f) + b_vv[c] + b_iv[c];
      s += x[j];
    }
#pragma unroll
    for (int o = 1; o <= 4; o <<= 1) s += __shfl_xor(s, o);
    float mu = s * (1.f / 64.f);
    float v = 0.f;
#pragma unroll
    for (int j = 0; j < 8; j++) { float dx = x[j] - mu; v = fmaf(dx, dx, v); }
#pragma unroll
    for (int o = 1; o <= 4; o <<= 1) v += __shfl_xor(v, o);
    float rstd = rsqrtf(v * (1.f / 64.f) + 1e-5f);
    if (eg8 == 0) {
      float4 o0, o1;
      float* ov = (float*)&o0;
#pragma unroll
      for (int j = 0; j < 4; j++) {
        int c = cg8 * 8 + j;
        ov[j] = (x[j] - mu) * rstd * ln_vg[c] + ln_vb[c];
      }
      ov = (float*)&o1;
#pragma unroll
      for (int j = 0; j < 4; j++) {
        int c = cg8 * 8 + 4 + j;
        ov[j] = (x[4 + j] - mu) * rstd * ln_vg[c] + ln_vb[c];
      }
      *(float4*)&out[(size_t)w * 64 + cg8 * 8]     = o0;
      *(float4*)&out[(size_t)w * 64 + cg8 * 8 + 4] = o1;
    }
  } else {
    int dd = blockIdx.x;
    int bfull = ptr_vi[dd], cntf = ptr_vi[dd + 1] - bfull;
    int q = (cntf + 3) >> 2;
    int off = min(wv * q, cntf);
    int cnt = min(q, cntf - off);
    int b = bfull + off;
    int es0 = 0, ea0 = 0;
    if (lane < cnt) { Edge e = e_vi[b + lane]; es0 = e.s; ea0 = *(const int*)&e.ea; }
    float4 hrr = *(const float4*)&hr_vi[(size_t)dd * 64 + cg8 * 8];
    float acc[8];
    float dn = 0.f;
    gatW1<false>(dd, lane, eg8, cg8, b, cnt, es0, ea0, e_vi, hl_vi, hrr, We_vi, att_vi, acc, dn);
    if (eg8 == 0) {
#pragma unroll
      for (int j = 0; j < 8; j++) sm[wv][cg8][j] = acc[j];
      sm[wv][cg8][8] = dn;
    }
    __syncthreads();
    if (wv == 0) {
#pragma unroll
      for (int j = 0; j < 8; j++)
        acc[j] = sm[0][cg8][j] + sm[1][cg8][j] + sm[2][cg8][j] + sm[3][cg8][j];
      dn = sm[0][cg8][8] + sm[1][cg8][8] + sm[2][cg8][8] + sm[3][cg8][8];
      float x[8], s = 0.f;
#pragma unroll
      for (int j = 0; j < 8; j++) {
        int c = cg8 * 8 + j;
        x[j] = acc[j] / (dn + 1e-16f) + b_vi[c];
        s += x[j];
      }
#pragma unroll
      for (int o = 1; o <= 4; o <<= 1) s += __shfl_xor(s, o);
      float mu = s * (1.f / 64.f);
      float v = 0.f;
#pragma unroll
      for (int j = 0; j < 8; j++) { float dx = x[j] - mu; v = fmaf(dx, dx, v); }
#pragma unroll
      for (int o = 1; o <= 4; o <<= 1) v += __shfl_xor(v, o);
      float rstd = rsqrtf(v * (1.f / 64.f) + 1e-5f);
      if (eg8 == 0) {
#pragma unroll
        for (int j = 0; j < 8; j++) {
          int c = cg8 * 8 + j;
          out[(size_t)(NV + dd) * 64 + c] = (x[j] - mu) * rstd * ln_rg[c] + ln_rb[c];
        }
      }
    }
  }
}

// ---------------- launch ----------------
extern "C" void kernel_launch(void* const* d_in, const int* in_sizes, int n_in,
                              void* d_out, int out_size, void* d_ws, size_t ws_size,
                              hipStream_t stream) {
  const float* x_veh  = (const float*)d_in[0];
  const float* x_rsu  = (const float*)d_in[1];
  const float* ea_vv  = (const float*)d_in[2];
  const float* ea_vi  = (const float*)d_in[3];
  const float* ea_iv  = (const float*)d_in[4];
  const int*   src_vv = (const int*)d_in[5];
  const int*   dst_vv = (const int*)d_in[6];
  const int*   src_vi = (const int*)d_in[7];
  const int*   dst_vi = (const int*)d_in[8];
  const int*   src_iv = (const int*)d_in[9];
  const int*   dst_iv = (const int*)d_in[10];
  const float* Wl_vv1 = (const float*)d_in[11];
  const float* Wr_vv1 = (const float*)d_in[12];
  const float* We_vv1 = (const float*)d_in[13];
  const float* att_vv1= (const float*)d_in[14];
  const float* b_vv1  = (const float*)d_in[15];
  const float* Wl_vi1 = (const float*)d_in[16];
  const float* Wr_vi1 = (const float*)d_in[17];
  const float* We_vi1 = (const float*)d_in[18];
  const float* att_vi1= (const float*)d_in[19];
  const float* b_vi1  = (const float*)d_in[20];
  const float* Wl_iv1 = (const float*)d_in[21];
  const float* Wr_iv1 = (const float*)d_in[22];
  const float* We_iv1 = (const float*)d_in[23];
  const float* att_iv1= (const float*)d_in[24];
  const float* b_iv1  = (const float*)d_in[25];
  const float* Wl_vv2 = (const float*)d_in[26];
  const float* Wr_vv2 = (const float*)d_in[27];
  const float* We_vv2 = (const float*)d_in[28];
  const float* att_vv2= (const float*)d_in[29];
  const float* b_vv2  = (const float*)d_in[30];
  const float* Wl_vi2 = (const float*)d_in[31];
  const float* Wr_vi2 = (const float*)d_in[32];
  const float* We_vi2 = (const float*)d_in[33];
  const float* att_vi2= (const float*)d_in[34];
  const float* b_vi2  = (const float*)d_in[35];
  const float* Wl_iv2 = (const float*)d_in[36];
  const float* Wr_iv2 = (const float*)d_in[37];
  const float* We_iv2 = (const float*)d_in[38];
  const float* att_iv2= (const float*)d_in[39];
  const float* b_iv2  = (const float*)d_in[40];
  const float* ln_vg  = (const float*)d_in[41];
  const float* ln_vb  = (const float*)d_in[42];
  const float* ln_rg  = (const float*)d_in[43];
  const float* ln_rb  = (const float*)d_in[44];

  float* ws  = (float*)d_ws;
  float* out = (float*)d_out;

  int* cur_vv = (int*)(ws + OFF_CUR_VV);
  int* cur_iv = (int*)(ws + OFF_CUR_IV);
  int* cur_vi = (int*)(ws + OFF_CUR_VI);
  int* ptr_vv = (int*)(ws + OFF_PTR_VV);
  int* ptr_iv = (int*)(ws + OFF_PTR_IV);
  int* ptr_vi = (int*)(ws + OFF_PTR_VI);
  Edge* e_vv = (Edge*)(ws + OFF_E_VV);
  Edge* e_iv = (Edge*)(ws + OFF_E_IV);
  Edge* e_vi = (Edge*)(ws + OFF_E_VI);
  TRec* tmp  = (TRec*)(ws + OFF_TMP);

  __half* hl_vv1 = (__half*)(ws + OFF_HL_VV1);
  __half* hr_vv1 = (__half*)(ws + OFF_HR_VV1);
  __half* hr_iv1 = (__half*)(ws + OFF_HR_IV1);
  __half* hl_vi1 = (__half*)(ws + OFF_HL_VI1);
  __half* hl_iv1 = (__half*)(ws + OFF_HL_IV1);
  __half* hr_vi1 = (__half*)(ws + OFF_HR_VI1);
  __half* v1 = (__half*)(ws + OFF_V1);
  __half* r1 = (__half*)(ws + OFF_R1);
  __half* hl_vv2 = (__half*)(ws + OFF_HL_VV2);
  __half* hr_vv2 = (__half*)(ws + OFF_HR_VV2);
  __half* hr_iv2 = (__half*)(ws + OFF_HR_IV2);
  __half* hl_vi2 = (__half*)(ws + OFF_HL_VI2);
  __half* hl_iv2 = (__half*)(ws + OFF_HL_IV2);
  __half* hr_vi2 = (__half*)(ws + OFF_HR_VI2);

  (void)hipMemsetAsync(ws, 0, ZERO_END * sizeof(float), stream);

  // fused: CSR build pass-1 (blocks first) + layer-1 GEMM (independent, overlaps)
  int nb_build = (ETOT + 255) / 256;
  int nbv1 = (NV + 7) / 8, nbr1 = (NR + 7) / 8;
  k_build1_gemm1<<<nb_build + nbv1 + nbr1, 256, 0, stream>>>(
      src_vv, dst_vv, ea_vv, src_iv, dst_iv, ea_iv, src_vi, dst_vi, ea_vi,
      cur_vv, cur_iv, cur_vi, tmp,
      x_veh, Wl_vv1, Wr_vv1, Wr_iv1, Wl_vi1, hl_vv1, hr_vv1, hr_iv1, hl_vi1,
      x_rsu, Wl_iv1, Wr_vi1, hl_iv1, hr_vi1,
      nb_build, nbv1);

  k_scan3<<<3, 1024, 0, stream>>>(cur_vv, ptr_vv, NV, cur_iv, ptr_iv, NV, cur_vi, ptr_vi, NR);
  k_build2<<<(ETOT + 255) / 256, 256, 0, stream>>>(tmp, ptr_vv, ptr_iv, ptr_vi,
      e_vv, e_iv, e_vi);

  // layer-1 fused aggregation
  k_gat_l1<<<NR + VB, 256, 0, stream>>>(
      ptr_vv, e_vv, hl_vv1, hr_vv1, We_vv1, att_vv1,
      ptr_iv, e_iv, hl_iv1, hr_iv1, We_iv1, att_iv1,
      ptr_vi, e_vi, hl_vi1, hr_vi1, We_vi1, att_vi1,
      b_vv1, b_iv1, b_vi1, v1, r1);

  // layer-2 dense transforms (veh + rsu combined)
  int nbv2 = (NV + 15) / 16, nbr2 = (NR + 15) / 16;
  k_gemm2c<<<nbv2 + nbr2, 256, 0, stream>>>(v1,
      Wl_vv2, Wr_vv2, Wr_iv2, Wl_vi2, hl_vv2, hr_vv2, hr_iv2, hl_vi2,
      r1, Wl_iv2, Wr_vi2, hl_iv2, hr_vi2, nbv2);

  // layer-2 fused aggregation + LayerNorm -> out
  k_gat_l2<<<NR + VB, 256, 0, stream>>>(
      ptr_vv, e_vv, hl_vv2, hr_vv2, We_vv2, att_vv2,
      ptr_iv, e_iv, hl_iv2, hr_iv2, We_iv2, att_iv2,
      ptr_vi, e_vi, hl_vi2, hr_vi2, We_vi2, att_vi2,
      b_vv2, b_iv2, b_vi2, ln_vg, ln_vb, ln_rg, ln_rb, out);
  (void)in_sizes; (void)n_in; (void)out_size; (void)ws_size;
}

// Round 16
// 297.665 us; speedup vs baseline: 1.4985x; 1.4985x over previous
//
#include <hip/hip_runtime.h>
#include <hip/hip_fp16.h>

// ---------------- problem constants ----------------
constexpr int NV = 30000, NR = 1000;
constexpr int EVV = 400000, EVI = 120000, EIV = 120000;
constexpr int ETOT = EVV + EIV + EVI;
constexpr int VB = (NV + 3) / 4;   // veh blocks in merged gat kernels
constexpr float LOFF = 4.0f;       // logit offset (cancels in softmax ratio)

struct __align__(8) Edge { int s; __half2 ea; };
struct __align__(16) TRec { int s; int d; __half2 ea; int r; };
typedef __half2 h2;

__device__ __forceinline__ h2 h2shfl_xor(h2 v, int m) {
  int i = *(int*)&v;
  i = __shfl_xor(i, m);
  return *(h2*)&i;
}
__device__ __forceinline__ h2 h2max(h2 a, h2 b) {
  h2 r;
  asm("v_pk_max_f16 %0, %1, %2" : "=v"(r) : "v"(a), "v"(b));
  return r;
}

// ---------------- workspace layout (float units) ----------------
constexpr size_t OFF_CUR_VV = 0;                        // NV (zeroed)
constexpr size_t OFF_CUR_IV = OFF_CUR_VV + NV;          // NV (zeroed)
constexpr size_t OFF_CUR_VI = OFF_CUR_IV + NV;          // NR (zeroed)
constexpr size_t ZERO_END   = OFF_CUR_VI + NR;
constexpr size_t OFF_PTR_VV = ZERO_END;                 // NV+2
constexpr size_t OFF_PTR_IV = OFF_PTR_VV + NV + 2;
constexpr size_t OFF_PTR_VI = OFF_PTR_IV + NV + 2;
constexpr size_t OFF_E_VV   = (OFF_PTR_VI + NR + 2 + 3) & ~(size_t)3;
constexpr size_t OFF_E_IV   = OFF_E_VV + (size_t)EVV * 2;
constexpr size_t OFF_E_VI   = OFF_E_IV + (size_t)EIV * 2;
constexpr size_t OFF_TMP    = (OFF_E_VI + (size_t)EVI * 2 + 3) & ~(size_t)3;  // TRec = 4 floats
constexpr size_t OFF_H      = (OFF_TMP + (size_t)ETOT * 4 + 3) & ~(size_t)3;
// layer-1 tables: 128 halves/row = 64 float-units/row (head-interleaved: pos p = c*2+h)
constexpr size_t OFF_HL_VV1 = OFF_H;
constexpr size_t OFF_HR_VV1 = OFF_HL_VV1 + (size_t)NV * 64;
constexpr size_t OFF_HR_IV1 = OFF_HR_VV1 + (size_t)NV * 64;
constexpr size_t OFF_HL_VI1 = OFF_HR_IV1 + (size_t)NV * 64;
constexpr size_t OFF_HL_IV1 = OFF_HL_VI1 + (size_t)NV * 64;
constexpr size_t OFF_HR_VI1 = OFF_HL_IV1 + (size_t)NR * 64;
constexpr size_t L1_END     = OFF_HR_VI1 + (size_t)NR * 64;
// v1/r1: fp16 standard channel order (128 halves/row)
constexpr size_t OFF_V1     = L1_END;
constexpr size_t OFF_R1     = OFF_V1 + (size_t)NV * 64;
constexpr size_t WS_END     = OFF_R1 + (size_t)NR * 64;
// layer-2 tables overlay layer-1 region: 64 halves/row (standard order)
constexpr size_t OFF_HL_VV2 = OFF_H;
constexpr size_t OFF_HR_VV2 = OFF_HL_VV2 + (size_t)NV * 32;
constexpr size_t OFF_HR_IV2 = OFF_HR_VV2 + (size_t)NV * 32;
constexpr size_t OFF_HL_VI2 = OFF_HR_IV2 + (size_t)NV * 32;
constexpr size_t OFF_HL_IV2 = OFF_HL_VI2 + (size_t)NV * 32;
constexpr size_t OFF_HR_VI2 = OFF_HL_IV2 + (size_t)NR * 32;
constexpr size_t L2_END     = OFF_HR_VI2 + (size_t)NR * 32;
static_assert(L2_END <= OFF_V1, "layer-2 overlay must not clobber v1/r1");

// ---------------- combined layer-1 GEMM body ----------------
template<int K, int NW>
__device__ __forceinline__ void gemm1_body(float* xs, int bid,
    const float* __restrict__ X,
    const float* __restrict__ W0, const float* __restrict__ W1,
    const float* __restrict__ W2, const float* __restrict__ W3,
    __half* __restrict__ Y0, __half* __restrict__ Y1,
    __half* __restrict__ Y2, __half* __restrict__ Y3, int n) {
  constexpr int ROWS = 8;
  int r0 = bid * ROWS;
  int tid = threadIdx.x;
  int col = tid & 127, grp = tid >> 7;
  for (int i = tid; i < ROWS * K; i += 256) {
    int gi = r0 * K + i;
    xs[i] = (gi < n * K) ? X[gi] : 0.f;
  }
  __syncthreads();
  int oidx = ((col & 63) << 1) + (col >> 6);
#pragma unroll
  for (int rep = 0; rep < NW / 2; rep++) {
    int wi = grp + rep * 2;
    const float* __restrict__ W = wi == 0 ? W0 : wi == 1 ? W1 : wi == 2 ? W2 : W3;
    __half* __restrict__ Y = wi == 0 ? Y0 : wi == 1 ? Y1 : wi == 2 ? Y2 : Y3;
    float acc[ROWS];
#pragma unroll
    for (int r = 0; r < ROWS; r++) acc[r] = 0.f;
#pragma unroll
    for (int k4 = 0; k4 < K / 4; k4++) {
      float w0 = W[(4 * k4 + 0) * 128 + col];
      float w1 = W[(4 * k4 + 1) * 128 + col];
      float w2 = W[(4 * k4 + 2) * 128 + col];
      float w3 = W[(4 * k4 + 3) * 128 + col];
#pragma unroll
      for (int r = 0; r < ROWS; r++) {
        float x0 = xs[r * K + 4 * k4], x1 = xs[r * K + 4 * k4 + 1];
        float x2 = xs[r * K + 4 * k4 + 2], x3 = xs[r * K + 4 * k4 + 3];
        acc[r] = fmaf(x0, w0, acc[r]);
        acc[r] = fmaf(x1, w1, acc[r]);
        acc[r] = fmaf(x2, w2, acc[r]);
        acc[r] = fmaf(x3, w3, acc[r]);
      }
    }
#pragma unroll
    for (int r = 0; r < ROWS; r++)
      if (r0 + r < n) Y[(size_t)(r0 + r) * 128 + oidx] = __float2half(acc[r]);
  }
}

// ---------------- fused CSR-build pass-1 + layer-1 GEMM (independent; overlap) ----------------
__global__ __launch_bounds__(256) void k_build1_gemm1(
    const int* __restrict__ svv, const int* __restrict__ dvv, const float* __restrict__ eavv,
    const int* __restrict__ siv, const int* __restrict__ div_, const float* __restrict__ eaiv,
    const int* __restrict__ svi, const int* __restrict__ dvi, const float* __restrict__ eavi,
    int* __restrict__ cvv, int* __restrict__ civ, int* __restrict__ cvi,
    TRec* __restrict__ tmp,
    const float* xv, const float* W0v, const float* W1v, const float* W2v, const float* W3v,
    __half* Y0v, __half* Y1v, __half* Y2v, __half* Y3v,
    const float* xr, const float* W0r, const float* W1r,
    __half* Y0r, __half* Y1r,
    int nb_build, int nbv) {
  __shared__ float xs[8 * 16];
  int bid = blockIdx.x;
  if (bid < nb_build) {
    int t = bid * 256 + threadIdx.x;
    if (t < EVV) {
      int d = dvv[t];
      float2 ea = *(const float2*)&eavv[2 * t];
      TRec rec; rec.s = svv[t]; rec.d = d;
      rec.ea = __floats2half2_rn(ea.x, ea.y);
      rec.r = atomicAdd(&cvv[d], 1);
      tmp[t] = rec;
    } else if (t < EVV + EIV) {
      int e = t - EVV, d = div_[e];
      float2 ea = *(const float2*)&eaiv[2 * e];
      TRec rec; rec.s = siv[e]; rec.d = d;
      rec.ea = __floats2half2_rn(ea.x, ea.y);
      rec.r = atomicAdd(&civ[d], 1);
      tmp[t] = rec;
    } else if (t < ETOT) {
      int e = t - EVV - EIV, d = dvi[e];
      float2 ea = *(const float2*)&eavi[2 * e];
      TRec rec; rec.s = svi[e]; rec.d = d;
      rec.ea = __floats2half2_rn(ea.x, ea.y);
      rec.r = atomicAdd(&cvi[d], 1);
      tmp[t] = rec;
    }
  } else if (bid < nb_build + nbv) {
    gemm1_body<16, 4>(xs, bid - nb_build, xv, W0v, W1v, W2v, W3v, Y0v, Y1v, Y2v, Y3v, NV);
  } else {
    gemm1_body<8, 2>(xs, bid - nb_build - nbv, xr, W0r, W1r, nullptr, nullptr,
                     Y0r, Y1r, nullptr, nullptr, NR);
  }
}

__global__ __launch_bounds__(1024) void k_scan3(
    const int* c0, int* p0, int n0,
    const int* c1, int* p1, int n1,
    const int* c2, int* p2, int n2) {
  const int* cnt = blockIdx.x == 0 ? c0 : blockIdx.x == 1 ? c1 : c2;
  int* ptr = blockIdx.x == 0 ? p0 : blockIdx.x == 1 ? p1 : p2;
  int n = blockIdx.x == 0 ? n0 : blockIdx.x == 1 ? n1 : n2;
  __shared__ int tsum[1024];
  int t = threadIdx.x;
  int per = (n + 1023) >> 10;
  int base = t * per;
  int s = 0;
  for (int i = 0; i < per; i++) { int idx = base + i; if (idx < n) s += cnt[idx]; }
  tsum[t] = s;
  for (int off = 1; off < 1024; off <<= 1) {
    __syncthreads();
    int v = (t >= off) ? tsum[t - off] : 0;
    __syncthreads();
    tsum[t] += v;
  }
  __syncthreads();
  int run = tsum[t] - s;
  for (int i = 0; i < per; i++) {
    int idx = base + i;
    if (idx < n) { ptr[idx] = run; run += cnt[idx]; }
  }
  if (t == 1023) ptr[n] = tsum[1023];
}

__global__ __launch_bounds__(256) void k_build2(
    const TRec* __restrict__ tmp,
    const int* __restrict__ pvv, const int* __restrict__ piv, const int* __restrict__ pvi,
    Edge* __restrict__ evv, Edge* __restrict__ eiv, Edge* __restrict__ evi) {
  int t = blockIdx.x * blockDim.x + threadIdx.x;
  if (t >= ETOT) return;
  TRec rec = tmp[t];
  Edge ed; ed.s = rec.s; ed.ea = rec.ea;
  if (t < EVV)            evv[pvv[rec.d] + rec.r] = ed;
  else if (t < EVV + EIV) eiv[piv[rec.d] + rec.r] = ed;
  else                    evi[pvi[rec.d] + rec.r] = ed;
}

// ---------------- combined layer-2 GEMM (veh + rsu in one launch) ----------------
template<int NW>
__device__ __forceinline__ void gemm2_body(float* xs, int bid,
    const __half* __restrict__ X,
    const float* __restrict__ W0, const float* __restrict__ W1,
    const float* __restrict__ W2, const float* __restrict__ W3,
    __half* __restrict__ Y0, __half* __restrict__ Y1,
    __half* __restrict__ Y2, __half* __restrict__ Y3, int n) {
  constexpr int ROWS = 16, K = 128;
  int r0 = bid * ROWS;
  int tid = threadIdx.x;
  const __half2* X2 = (const __half2*)X;
  for (int i = tid; i < ROWS * K / 2; i += 256) {
    int gi = r0 * (K / 2) + i;
    float2 f = (gi < n * (K / 2)) ? __half22float2(X2[gi]) : make_float2(0.f, 0.f);
    xs[2 * i] = f.x;
    xs[2 * i + 1] = f.y;
  }
  __syncthreads();
  int lane = tid & 63, wv = tid >> 6;
  if (wv >= NW) return;
  const float* __restrict__ W = wv == 0 ? W0 : wv == 1 ? W1 : wv == 2 ? W2 : W3;
  __half* __restrict__ Y = wv == 0 ? Y0 : wv == 1 ? Y1 : wv == 2 ? Y2 : Y3;
  float acc[ROWS];
#pragma unroll
  for (int r = 0; r < ROWS; r++) acc[r] = 0.f;
  for (int k4 = 0; k4 < K / 4; k4++) {
    float w0 = W[(4 * k4 + 0) * 64 + lane];
    float w1 = W[(4 * k4 + 1) * 64 + lane];
    float w2 = W[(4 * k4 + 2) * 64 + lane];
    float w3 = W[(4 * k4 + 3) * 64 + lane];
#pragma unroll
    for (int r = 0; r < ROWS; r++) {
      float x0 = xs[r * K + 4 * k4], x1 = xs[r * K + 4 * k4 + 1];
      float x2 = xs[r * K + 4 * k4 + 2], x3 = xs[r * K + 4 * k4 + 3];
      acc[r] = fmaf(x0, w0, acc[r]);
      acc[r] = fmaf(x1, w1, acc[r]);
      acc[r] = fmaf(x2, w2, acc[r]);
      acc[r] = fmaf(x3, w3, acc[r]);
    }
  }
#pragma unroll
  for (int r = 0; r < ROWS; r++)
    if (r0 + r < n) Y[(size_t)(r0 + r) * 64 + lane] = __float2half(acc[r]);
}

__global__ __launch_bounds__(256) void k_gemm2c(
    const __half* xv, const float* W0v, const float* W1v, const float* W2v, const float* W3v,
    __half* Y0v, __half* Y1v, __half* Y2v, __half* Y3v,
    const __half* xr, const float* W0r, const float* W1r,
    __half* Y0r, __half* Y1r, int nbv) {
  __shared__ float xs[16 * 128];
  if ((int)blockIdx.x < nbv)
    gemm2_body<4>(xs, blockIdx.x, xv, W0v, W1v, W2v, W3v, Y0v, Y1v, Y2v, Y3v, NV);
  else
    gemm2_body<2>(xs, blockIdx.x - nbv, xr, W0r, W1r, nullptr, nullptr,
                  Y0r, Y1r, nullptr, nullptr, NR);
}

// ---------------- window-preloaded GATv2 (pk-fp16; window0 + hr preloaded by caller) ----------------

// layer-1: H=2, head-interleaved rows, 16-lane groups; 16-chunk + 4-stride tail
template<bool SELF>
__device__ __forceinline__ void gatW2(int d, int lane, int eg, int cg,
    int b, int cnt, int es0, int eab0,
    const Edge* __restrict__ ed,
    const __half* __restrict__ hl, float4 hrr,
    const float* __restrict__ We, const float* __restrict__ att,
    float* acc, float& den0, float& den1) {
  h2 hrc2[4], av2[4], w02[4], w12[4];
  const h2* hrp = (const h2*)&hrr;
#pragma unroll
  for (int j = 0; j < 4; j++) hrc2[j] = hrp[j];
#pragma unroll
  for (int j = 0; j < 4; j++) {
    int c = cg * 4 + j;
    av2[j] = __floats2half2_rn(att[c], att[64 + c]);
    w02[j] = __floats2half2_rn(We[c], We[64 + c]);
    w12[j] = __floats2half2_rn(We[128 + c], We[192 + c]);
  }
  const h2 c02 = __float2half2_rn(0.2f);
  h2 acc2[4];
#pragma unroll
  for (int j = 0; j < 4; j++) acc2[j] = __float2half2_rn(0.f);
  float sum0 = 0.f, sum1 = 0.f;
  auto proc = [&](float4 r, int eab, bool v) {
    const h2* hp = (const h2*)&r;
    h2 eh = *(h2*)&eab;
    h2 ef0 = __low2half2(eh), ef1 = __high2half2(eh);
    h2 lacc = __float2half2_rn(0.f);
#pragma unroll
    for (int j = 0; j < 4; j++) {
      h2 g = __hfma2(ef0, w02[j], __hadd2(hp[j], hrc2[j]));
      g = __hfma2(ef1, w12[j], g);
      h2 lr = h2max(g, __hmul2(c02, g));
      lacc = __hfma2(lr, av2[j], lacc);
    }
#pragma unroll
    for (int o = 1; o <= 8; o <<= 1) lacc = __hadd2(lacc, h2shfl_xor(lacc, o));
    float2 lf = __half22float2(lacc);
    float ex0 = v ? __expf(lf.x - LOFF) : 0.f;
    float ex1 = v ? __expf(lf.y - LOFF) : 0.f;
    h2 exh = __floats2half2_rn(ex0, ex1);
#pragma unroll
    for (int j = 0; j < 4; j++) acc2[j] = __hfma2(exh, hp[j], acc2[j]);
    den0 += ex0; den1 += ex1;
  };
  auto doWin = [&](int es, int eab, int wlen) {
    int kk = 0;
    for (; kk + 16 <= wlen; kk += 16) {
      int k0 = kk + eg, k1 = kk + 4 + eg, k2 = kk + 8 + eg, k3 = kk + 12 + eg;
      int s0 = __shfl(es, k0), ea0 = __shfl(eab, k0);
      int s1 = __shfl(es, k1), ea1 = __shfl(eab, k1);
      int s2 = __shfl(es, k2), ea2 = __shfl(eab, k2);
      int s3 = __shfl(es, k3), ea3 = __shfl(eab, k3);
      float4 r0 = *(const float4*)&hl[(size_t)s0 * 128 + cg * 8];
      float4 r1 = *(const float4*)&hl[(size_t)s1 * 128 + cg * 8];
      float4 r2 = *(const float4*)&hl[(size_t)s2 * 128 + cg * 8];
      float4 r3 = *(const float4*)&hl[(size_t)s3 * 128 + cg * 8];
      proc(r0, ea0, true);
      proc(r1, ea1, true);
      proc(r2, ea2, true);
      proc(r3, ea3, true);
    }
    for (; kk < wlen; kk += 4) {
      int k0 = kk + eg;
      int s0 = __shfl(es, k0), ea0 = __shfl(eab, k0);
      float4 r0 = *(const float4*)&hl[(size_t)s0 * 128 + cg * 8];
      proc(r0, ea0, k0 < wlen);
    }
  };
  if (SELF) {
    float2 f = __half22float2(*(h2*)&eab0);
    sum0 += f.x; sum1 += f.y;
  }
  doWin(es0, eab0, min(64, cnt));
  for (int wf = 64; wf < cnt; wf += 64) {
    int idx = wf + lane;
    int es = 0, eab = 0;
    if (idx < cnt) { Edge e = ed[b + idx]; es = e.s; eab = *(const int*)&e.ea; }
    if (SELF) {
      float2 f = __half22float2(*(h2*)&eab);
      sum0 += f.x; sum1 += f.y;
    }
    doWin(es, eab, min(64, cnt - wf));
  }
  if (SELF) {
#pragma unroll
    for (int o = 1; o <= 32; o <<= 1) { sum0 += __shfl_xor(sum0, o); sum1 += __shfl_xor(sum1, o); }
    float dg = fmaxf((float)cnt, 1.f);
    __half2 mh = __floats2half2_rn(sum0 / dg, sum1 / dg);
    int meab = *(const int*)&mh;
    float4 rS = *(const float4*)&hl[(size_t)d * 128 + cg * 8];
    proc(rS, meab, eg == 0);
  }
#pragma unroll
  for (int o = 16; o <= 32; o <<= 1) {
#pragma unroll
    for (int j = 0; j < 4; j++) acc2[j] = __hadd2(acc2[j], h2shfl_xor(acc2[j], o));
    den0 += __shfl_xor(den0, o);
    den1 += __shfl_xor(den1, o);
  }
#pragma unroll
  for (int j = 0; j < 4; j++) {
    float2 f = __half22float2(acc2[j]);
    acc[2 * j] = f.x; acc[2 * j + 1] = f.y;
  }
}

// layer-2: H=1, standard rows, 8-lane groups; 32-chunk + 8-stride tail
template<bool SELF>
__device__ __forceinline__ void gatW1(int d, int lane, int eg8, int cg8,
    int b, int cnt, int es0, int eab0,
    const Edge* __restrict__ ed,
    const __half* __restrict__ hl, float4 hrr,
    const float* __restrict__ We, const float* __restrict__ att,
    float* acc, float& den) {
  h2 hrc2[4], av2[4], w02[4], w12[4];
  const h2* hrp = (const h2*)&hrr;
#pragma unroll
  for (int j = 0; j < 4; j++) hrc2[j] = hrp[j];
#pragma unroll
  for (int j = 0; j < 4; j++) {
    int c = cg8 * 8 + 2 * j;
    av2[j] = __floats2half2_rn(att[c], att[c + 1]);
    w02[j] = __floats2half2_rn(We[c], We[c + 1]);
    w12[j] = __floats2half2_rn(We[64 + c], We[64 + c + 1]);
  }
  const h2 c02 = __float2half2_rn(0.2f);
  h2 acc2[4];
#pragma unroll
  for (int j = 0; j < 4; j++) acc2[j] = __float2half2_rn(0.f);
  float sum0 = 0.f, sum1 = 0.f;
  auto proc = [&](float4 r, int eab, bool v) {
    const h2* hp = (const h2*)&r;
    h2 eh = *(h2*)&eab;
    h2 ef0 = __low2half2(eh), ef1 = __high2half2(eh);
    h2 lacc = __float2half2_rn(0.f);
#pragma unroll
    for (int j = 0; j < 4; j++) {
      h2 g = __hfma2(ef0, w02[j], __hadd2(hp[j], hrc2[j]));
      g = __hfma2(ef1, w12[j], g);
      h2 lr = h2max(g, __hmul2(c02, g));
      lacc = __hfma2(lr, av2[j], lacc);
    }
#pragma unroll
    for (int o = 1; o <= 4; o <<= 1) lacc = __hadd2(lacc, h2shfl_xor(lacc, o));
    float2 lf = __half22float2(lacc);
    float ex = v ? __expf(lf.x + lf.y - LOFF) : 0.f;
    h2 exh = __float2half2_rn(ex);
#pragma unroll
    for (int j = 0; j < 4; j++) acc2[j] = __hfma2(exh, hp[j], acc2[j]);
    den += ex;
  };
  auto doWin = [&](int es, int eab, int wlen) {
    int kk = 0;
    for (; kk + 32 <= wlen; kk += 32) {
      int k0 = kk + eg8, k1 = kk + 8 + eg8, k2 = kk + 16 + eg8, k3 = kk + 24 + eg8;
      int s0 = __shfl(es, k0), ea0 = __shfl(eab, k0);
      int s1 = __shfl(es, k1), ea1 = __shfl(eab, k1);
      int s2 = __shfl(es, k2), ea2 = __shfl(eab, k2);
      int s3 = __shfl(es, k3), ea3 = __shfl(eab, k3);
      float4 r0 = *(const float4*)&hl[(size_t)s0 * 64 + cg8 * 8];
      float4 r1 = *(const float4*)&hl[(size_t)s1 * 64 + cg8 * 8];
      float4 r2 = *(const float4*)&hl[(size_t)s2 * 64 + cg8 * 8];
      float4 r3 = *(const float4*)&hl[(size_t)s3 * 64 + cg8 * 8];
      proc(r0, ea0, true);
      proc(r1, ea1, true);
      proc(r2, ea2, true);
      proc(r3, ea3, true);
    }
    for (; kk < wlen; kk += 8) {
      int k0 = kk + eg8;
      int s0 = __shfl(es, k0), ea0 = __shfl(eab, k0);
      float4 r0 = *(const float4*)&hl[(size_t)s0 * 64 + cg8 * 8];
      proc(r0, ea0, k0 < wlen);
    }
  };
  if (SELF) {
    float2 f = __half22float2(*(h2*)&eab0);
    sum0 += f.x; sum1 += f.y;
  }
  doWin(es0, eab0, min(64, cnt));
  for (int wf = 64; wf < cnt; wf += 64) {
    int idx = wf + lane;
    int es = 0, eab = 0;
    if (idx < cnt) { Edge e = ed[b + idx]; es = e.s; eab = *(const int*)&e.ea; }
    if (SELF) {
      float2 f = __half22float2(*(h2*)&eab);
      sum0 += f.x; sum1 += f.y;
    }
    doWin(es, eab, min(64, cnt - wf));
  }
  if (SELF) {
#pragma unroll
    for (int o = 1; o <= 32; o <<= 1) { sum0 += __shfl_xor(sum0, o); sum1 += __shfl_xor(sum1, o); }
    float dg = fmaxf((float)cnt, 1.f);
    __half2 mh = __floats2half2_rn(sum0 / dg, sum1 / dg);
    int meab = *(const int*)&mh;
    float4 rS = *(const float4*)&hl[(size_t)d * 64 + cg8 * 8];
    proc(rS, meab, eg8 == 0);
  }
#pragma unroll
  for (int o = 8; o <= 32; o <<= 1) {
#pragma unroll
    for (int j = 0; j < 4; j++) acc2[j] = __hadd2(acc2[j], h2shfl_xor(acc2[j], o));
    den += __shfl_xor(den, o);
  }
#pragma unroll
  for (int j = 0; j < 4; j++) {
    float2 f = __half22float2(acc2[j]);
    acc[2 * j] = f.x; acc[2 * j + 1] = f.y;
  }
}

// layer-1 merged: blocks [0,NR) = rsu (block/dst), [NR,NR+VB) = veh (wave/dst)
__global__ __launch_bounds__(256) void k_gat_l1(
    const int* ptr_vv, const Edge* e_vv,
    const __half* hl_vv, const __half* hr_vv, const float* We_vv, const float* att_vv,
    const int* ptr_iv, const Edge* e_iv,
    const __half* hl_iv, const __half* hr_iv, const float* We_iv, const float* att_iv,
    const int* ptr_vi, const Edge* e_vi,
    const __half* hl_vi, const __half* hr_vi, const float* We_vi, const float* att_vi,
    const float* b_vv, const float* b_iv, const float* b_vi,
    __half* __restrict__ v1, __half* __restrict__ r1) {
  __shared__ float sm[4][16][10];
  int lane = threadIdx.x & 63, wv = threadIdx.x >> 6;
  int eg = lane >> 4, cg = lane & 15;
  if (blockIdx.x >= NR) {
    int w = (blockIdx.x - NR) * 4 + wv;
    if (w >= NV) return;
    int b1 = ptr_vv[w], c1 = ptr_vv[w + 1] - b1;
    int b2 = ptr_iv[w], c2 = ptr_iv[w + 1] - b2;
    int es1 = 0, ea1 = 0, es2 = 0, ea2 = 0;
    if (lane < c1) { Edge e = e_vv[b1 + lane]; es1 = e.s; ea1 = *(const int*)&e.ea; }
    if (lane < c2) { Edge e = e_iv[b2 + lane]; es2 = e.s; ea2 = *(const int*)&e.ea; }
    float4 hrv = *(const float4*)&hr_vv[(size_t)w * 128 + cg * 8];
    float4 hri = *(const float4*)&hr_iv[(size_t)w * 128 + cg * 8];
    float acc[8];
    float d0 = 0.f, d1 = 0.f, oc[8];
    gatW2<true>(w, lane, eg, cg, b1, c1, es1, ea1, e_vv, hl_vv, hrv, We_vv, att_vv, acc, d0, d1);
#pragma unroll
    for (int j = 0; j < 8; j++) oc[j] = acc[j] / (((j & 1) ? d1 : d0) + 1e-16f);
    d0 = d1 = 0.f;
    gatW2<false>(w, lane, eg, cg, b2, c2, es2, ea2, e_iv, hl_iv, hri, We_iv, att_iv, acc, d0, d1);
#pragma unroll
    for (int j = 0; j < 8; j++) oc[j] += acc[j] / (((j & 1) ? d1 : d0) + 1e-16f);
    if (eg == 0) {
      float x[8];
#pragma unroll
      for (int j = 0; j < 8; j++) {
        int c = cg * 4 + (j >> 1);
        int idx = (j & 1) * 64 + c;
        float v = oc[j] + b_vv[idx] + b_iv[idx];
        x[j] = v > 0.f ? v : __expf(v) - 1.f;
      }
      __half2 h0a = __floats2half2_rn(x[0], x[2]), h0b = __floats2half2_rn(x[4], x[6]);
      __half2 h1a = __floats2half2_rn(x[1], x[3]), h1b = __floats2half2_rn(x[5], x[7]);
      float2 p0, p1;
      ((__half2*)&p0)[0] = h0a; ((__half2*)&p0)[1] = h0b;
      ((__half2*)&p1)[0] = h1a; ((__half2*)&p1)[1] = h1b;
      *(float2*)&v1[(size_t)w * 128 + cg * 4]      = p0;
      *(float2*)&v1[(size_t)w * 128 + 64 + cg * 4] = p1;
    }
  } else {
    int dd = blockIdx.x;
    int bfull = ptr_vi[dd], cntf = ptr_vi[dd + 1] - bfull;
    int q = (cntf + 3) >> 2;
    int off = min(wv * q, cntf);
    int cnt = min(q, cntf - off);
    int b = bfull + off;
    int es0 = 0, ea0 = 0;
    if (lane < cnt) { Edge e = e_vi[b + lane]; es0 = e.s; ea0 = *(const int*)&e.ea; }
    float4 hrr = *(const float4*)&hr_vi[(size_t)dd * 128 + cg * 8];
    float acc[8];
    float d0 = 0.f, d1 = 0.f;
    gatW2<false>(dd, lane, eg, cg, b, cnt, es0, ea0, e_vi, hl_vi, hrr, We_vi, att_vi, acc, d0, d1);
    if (eg == 0) {
#pragma unroll
      for (int j = 0; j < 8; j++) sm[wv][cg][j] = acc[j];
      sm[wv][cg][8] = d0; sm[wv][cg][9] = d1;
    }
    __syncthreads();
    if (wv == 0) {
#pragma unroll
      for (int j = 0; j < 8; j++)
        acc[j] = sm[0][cg][j] + sm[1][cg][j] + sm[2][cg][j] + sm[3][cg][j];
      d0 = sm[0][cg][8] + sm[1][cg][8] + sm[2][cg][8] + sm[3][cg][8];
      d1 = sm[0][cg][9] + sm[1][cg][9] + sm[2][cg][9] + sm[3][cg][9];
      if (eg == 0) {
        float x[8];
#pragma unroll
        for (int j = 0; j < 8; j++) {
          int c = cg * 4 + (j >> 1);
          int idx = (j & 1) * 64 + c;
          float v = acc[j] / (((j & 1) ? d1 : d0) + 1e-16f) + b_vi[idx];
          x[j] = v > 0.f ? v : __expf(v) - 1.f;
        }
        __half2 h0a = __floats2half2_rn(x[0], x[2]), h0b = __floats2half2_rn(x[4], x[6]);
        __half2 h1a = __floats2half2_rn(x[1], x[3]), h1b = __floats2half2_rn(x[5], x[7]);
        float2 p0, p1;
        ((__half2*)&p0)[0] = h0a; ((__half2*)&p0)[1] = h0b;
        ((__half2*)&p1)[0] = h1a; ((__half2*)&p1)[1] = h1b;
        *(float2*)&r1[(size_t)dd * 128 + cg * 4]      = p0;
        *(float2*)&r1[(size_t)dd * 128 + 64 + cg * 4] = p1;
      }
    }
  }
}

// layer-2 merged: rsu blocks first; veh rows -> out[0..NV), rsu -> out[NV..)
__global__ __launch_bounds__(256) void k_gat_l2(
    const int* ptr_vv, const Edge* e_vv,
    const __half* hl_vv, const __half* hr_vv, const float* We_vv, const float* att_vv,
    const int* ptr_iv, const Edge* e_iv,
    const __half* hl_iv, const __half* hr_iv, const float* We_iv, const float* att_iv,
    const int* ptr_vi, const Edge* e_vi,
    const __half* hl_vi, const __half* hr_vi, const float* We_vi, const float* att_vi,
    const float* b_vv, const float* b_iv, const float* b_vi,
    const float* ln_vg, const float* ln_vb, const float* ln_rg, const float* ln_rb,
    float* __restrict__ out) {
  __shared__ float sm[4][8][9];
  int lane = threadIdx.x & 63, wv = threadIdx.x >> 6;
  int eg8 = lane >> 3, cg8 = lane & 7;
  if (blockIdx.x >= NR) {
    int w = (blockIdx.x - NR) * 4 + wv;
    if (w >= NV) return;
    int b1 = ptr_vv[w], c1 = ptr_vv[w + 1] - b1;
    int b2 = ptr_iv[w], c2 = ptr_iv[w + 1] - b2;
    int es1 = 0, ea1 = 0, es2 = 0, ea2 = 0;
    if (lane < c1) { Edge e = e_vv[b1 + lane]; es1 = e.s; ea1 = *(const int*)&e.ea; }
    if (lane < c2) { Edge e = e_iv[b2 + lane]; es2 = e.s; ea2 = *(const int*)&e.ea; }
    float4 hrv = *(const float4*)&hr_vv[(size_t)w * 64 + cg8 * 8];
    float4 hri = *(const float4*)&hr_iv[(size_t)w * 64 + cg8 * 8];
    float acc[8];
    float dn = 0.f, oc[8];
    gatW1<true>(w, lane, eg8, cg8, b1, c1, es1, ea1, e_vv, hl_vv, hrv, We_vv, att_vv, acc, dn);
#pragma unroll
    for (int j = 0; j < 8; j++) oc[j] = acc[j] / (dn + 1e-16f);
    dn = 0.f;
    gatW1<false>(w, lane, eg8, cg8, b2, c2, es2, ea2, e_iv, hl_iv, hri, We_iv, att_iv, acc, dn);
    float x[8], s = 0.f;
#pragma unroll
    for (int j = 0; j < 8; j++) {
      int c = cg8 * 8 + j;
      x[j] = oc[j] + acc[j] / (dn + 1e-16f) + b_vv[c] + b_iv[c];
      s += x[j];
    }
#pragma unroll
    for (int o = 1; o <= 4; o <<= 1) s += __shfl_xor(s, o);
    float mu = s * (1.f / 64.f);
    float v = 0.f;
#pragma unroll
    for (int j = 0; j < 8; j++) { float dx = x[j] - mu; v = fmaf(dx, dx, v); }
#pragma unroll
    for (int o = 1; o <= 4; o <<= 1) v += __shfl_xor(v, o);
    float rstd = rsqrtf(v * (1.f / 64.f) + 1e-5f);
    if (eg8 == 0) {
      float4 o0, o1;
      float* ov = (float*)&o0;
#pragma unroll
      for (int j = 0; j < 4; j++) {
        int c = cg8 * 8 + j;
        ov[j] = (x[j] - mu) * rstd * ln_vg[c] + ln_vb[c];
      }
      ov = (float*)&o1;
#pragma unroll
      for (int j = 0; j < 4; j++) {
        int c = cg8 * 8 + 4 + j;
        ov[j] = (x[4 + j] - mu) * rstd * ln_vg[c] + ln_vb[c];
      }
      *(float4*)&out[(size_t)w * 64 + cg8 * 8]     = o0;
      *(float4*)&out[(size_t)w * 64 + cg8 * 8 + 4] = o1;
    }
  } else {
    int dd = blockIdx.x;
    int bfull = ptr_vi[dd], cntf = ptr_vi[dd + 1] - bfull;
    int q = (cntf + 3) >> 2;
    int off = min(wv * q, cntf);
    int cnt = min(q, cntf - off);
    int b = bfull + off;
    int es0 = 0, ea0 = 0;
    if (lane < cnt) { Edge e = e_vi[b + lane]; es0 = e.s; ea0 = *(const int*)&e.ea; }
    float4 hrr = *(const float4*)&hr_vi[(size_t)dd * 64 + cg8 * 8];
    float acc[8];
    float dn = 0.f;
    gatW1<false>(dd, lane, eg8, cg8, b, cnt, es0, ea0, e_vi, hl_vi, hrr, We_vi, att_vi, acc, dn);
    if (eg8 == 0) {
#pragma unroll
      for (int j = 0; j < 8; j++) sm[wv][cg8][j] = acc[j];
      sm[wv][cg8][8] = dn;
    }
    __syncthreads();
    if (wv == 0) {
#pragma unroll
      for (int j = 0; j < 8; j++)
        acc[j] = sm[0][cg8][j] + sm[1][cg8][j] + sm[2][cg8][j] + sm[3][cg8][j];
      dn = sm[0][cg8][8] + sm[1][cg8][8] + sm[2][cg8][8] + sm[3][cg8][8];
      float x[8], s = 0.f;
#pragma unroll
      for (int j = 0; j < 8; j++) {
        int c = cg8 * 8 + j;
        x[j] = acc[j] / (dn + 1e-16f) + b_vi[c];
        s += x[j];
      }
#pragma unroll
      for (int o = 1; o <= 4; o <<= 1) s += __shfl_xor(s, o);
      float mu = s * (1.f / 64.f);
      float v = 0.f;
#pragma unroll
      for (int j = 0; j < 8; j++) { float dx = x[j] - mu; v = fmaf(dx, dx, v); }
#pragma unroll
      for (int o = 1; o <= 4; o <<= 1) v += __shfl_xor(v, o);
      float rstd = rsqrtf(v * (1.f / 64.f) + 1e-5f);
      if (eg8 == 0) {
#pragma unroll
        for (int j = 0; j < 8; j++) {
          int c = cg8 * 8 + j;
          out[(size_t)(NV + dd) * 64 + c] = (x[j] - mu) * rstd * ln_rg[c] + ln_rb[c];
        }
      }
    }
  }
}

// ---------------- launch ----------------
extern "C" void kernel_launch(void* const* d_in, const int* in_sizes, int n_in,
                              void* d_out, int out_size, void* d_ws, size_t ws_size,
                              hipStream_t stream) {
  const float* x_veh  = (const float*)d_in[0];
  const float* x_rsu  = (const float*)d_in[1];
  const float* ea_vv  = (const float*)d_in[2];
  const float* ea_vi  = (const float*)d_in[3];
  const float* ea_iv  = (const float*)d_in[4];
  const int*   src_vv = (const int*)d_in[5];
  const int*   dst_vv = (const int*)d_in[6];
  const int*   src_vi = (const int*)d_in[7];
  const int*   dst_vi = (const int*)d_in[8];
  const int*   src_iv = (const int*)d_in[9];
  const int*   dst_iv = (const int*)d_in[10];
  const float* Wl_vv1 = (const float*)d_in[11];
  const float* Wr_vv1 = (const float*)d_in[12];
  const float* We_vv1 = (const float*)d_in[13];
  const float* att_vv1= (const float*)d_in[14];
  const float* b_vv1  = (const float*)d_in[15];
  const float* Wl_vi1 = (const float*)d_in[16];
  const float* Wr_vi1 = (const float*)d_in[17];
  const float* We_vi1 = (const float*)d_in[18];
  const float* att_vi1= (const float*)d_in[19];
  const float* b_vi1  = (const float*)d_in[20];
  const float* Wl_iv1 = (const float*)d_in[21];
  const float* Wr_iv1 = (const float*)d_in[22];
  const float* We_iv1 = (const float*)d_in[23];
  const float* att_iv1= (const float*)d_in[24];
  const float* b_iv1  = (const float*)d_in[25];
  const float* Wl_vv2 = (const float*)d_in[26];
  const float* Wr_vv2 = (const float*)d_in[27];
  const float* We_vv2 = (const float*)d_in[28];
  const float* att_vv2= (const float*)d_in[29];
  const float* b_vv2  = (const float*)d_in[30];
  const float* Wl_vi2 = (const float*)d_in[31];
  const float* Wr_vi2 = (const float*)d_in[32];
  const float* We_vi2 = (const float*)d_in[33];
  const float* att_vi2= (const float*)d_in[34];
  const float* b_vi2  = (const float*)d_in[35];
  const float* Wl_iv2 = (const float*)d_in[36];
  const float* Wr_iv2 = (const float*)d_in[37];
  const float* We_iv2 = (const float*)d_in[38];
  const float* att_iv2= (const float*)d_in[39];
  const float* b_iv2  = (const float*)d_in[40];
  const float* ln_vg  = (const float*)d_in[41];
  const float* ln_vb  = (const float*)d_in[42];
  const float* ln_rg  = (const float*)d_in[43];
  const float* ln_rb  = (const float*)d_in[44];

  float* ws  = (float*)d_ws;
  float* out = (float*)d_out;

  int* cur_vv = (int*)(ws + OFF_CUR_VV);
  int* cur_iv = (int*)(ws + OFF_CUR_IV);
  int* cur_vi = (int*)(ws + OFF_CUR_VI);
  int* ptr_vv = (int*)(ws + OFF_PTR_VV);
  int* ptr_iv = (int*)(ws + OFF_PTR_IV);
  int* ptr_vi = (int*)(ws + OFF_PTR_VI);
  Edge* e_vv = (Edge*)(ws + OFF_E_VV);
  Edge* e_iv = (Edge*)(ws + OFF_E_IV);
  Edge* e_vi = (Edge*)(ws + OFF_E_VI);
  TRec* tmp  = (TRec*)(ws + OFF_TMP);

  __half* hl_vv1 = (__half*)(ws + OFF_HL_VV1);
  __half* hr_vv1 = (__half*)(ws + OFF_HR_VV1);
  __half* hr_iv1 = (__half*)(ws + OFF_HR_IV1);
  __half* hl_vi1 = (__half*)(ws + OFF_HL_VI1);
  __half* hl_iv1 = (__half*)(ws + OFF_HL_IV1);
  __half* hr_vi1 = (__half*)(ws + OFF_HR_VI1);
  __half* v1 = (__half*)(ws + OFF_V1);
  __half* r1 = (__half*)(ws + OFF_R1);
  __half* hl_vv2 = (__half*)(ws + OFF_HL_VV2);
  __half* hr_vv2 = (__half*)(ws + OFF_HR_VV2);
  __half* hr_iv2 = (__half*)(ws + OFF_HR_IV2);
  __half* hl_vi2 = (__half*)(ws + OFF_HL_VI2);
  __half* hl_iv2 = (__half*)(ws + OFF_HL_IV2);
  __half* hr_vi2 = (__half*)(ws + OFF_HR_VI2);

  (void)hipMemsetAsync(ws, 0, ZERO_END * sizeof(float), stream);

  // fused: CSR build pass-1 (blocks first) + layer-1 GEMM (independent, overlaps)
  int nb_build = (ETOT + 255) / 256;
  int nbv1 = (NV + 7) / 8, nbr1 = (NR + 7) / 8;
  k_build1_gemm1<<<nb_build + nbv1 + nbr1, 256, 0, stream>>>(
      src_vv, dst_vv, ea_vv, src_iv, dst_iv, ea_iv, src_vi, dst_vi, ea_vi,
      cur_vv, cur_iv, cur_vi, tmp,
      x_veh, Wl_vv1, Wr_vv1, Wr_iv1, Wl_vi1, hl_vv1, hr_vv1, hr_iv1, hl_vi1,
      x_rsu, Wl_iv1, Wr_vi1, hl_iv1, hr_vi1,
      nb_build, nbv1);

  k_scan3<<<3, 1024, 0, stream>>>(cur_vv, ptr_vv, NV, cur_iv, ptr_iv, NV, cur_vi, ptr_vi, NR);
  k_build2<<<(ETOT + 255) / 256, 256, 0, stream>>>(tmp, ptr_vv, ptr_iv, ptr_vi,
      e_vv, e_iv, e_vi);

  // layer-1 fused aggregation
  k_gat_l1<<<NR + VB, 256, 0, stream>>>(
      ptr_vv, e_vv, hl_vv1, hr_vv1, We_vv1, att_vv1,
      ptr_iv, e_iv, hl_iv1, hr_iv1, We_iv1, att_iv1,
      ptr_vi, e_vi, hl_vi1, hr_vi1, We_vi1, att_vi1,
      b_vv1, b_iv1, b_vi1, v1, r1);

  // layer-2 dense transforms (veh + rsu combined)
  int nbv2 = (NV + 15) / 16, nbr2 = (NR + 15) / 16;
  k_gemm2c<<<nbv2 + nbr2, 256, 0, stream>>>(v1,
      Wl_vv2, Wr_vv2, Wr_iv2, Wl_vi2, hl_vv2, hr_vv2, hr_iv2, hl_vi2,
      r1, Wl_iv2, Wr_vi2, hl_iv2, hr_vi2, nbv2);

  // layer-2 fused aggregation + LayerNorm -> out
  k_gat_l2<<<NR + VB, 256, 0, stream>>>(
      ptr_vv, e_vv, hl_vv2, hr_vv2, We_vv2, att_vv2,
      ptr_iv, e_iv, hl_iv2, hr_iv2, We_iv2, att_iv2,
      ptr_vi, e_vi, hl_vi2, hr_vi2, We_vi2, att_vi2,
      b_vv2, b_iv2, b_vi2, ln_vg, ln_vb, ln_rg, ln_rb, out);
  (void)in_sizes; (void)n_in; (void)out_size; (void)ws_size;
}

// Round 17
// 297.156 us; speedup vs baseline: 1.5011x; 1.0017x over previous
//
#include <hip/hip_runtime.h>
#include <hip/hip_fp16.h>

// ---------------- problem constants ----------------
constexpr int NV = 30000, NR = 1000;
constexpr int EVV = 400000, EVI = 120000, EIV = 120000;
constexpr int ETOT = EVV + EIV + EVI;
constexpr int VB = (NV + 3) / 4;   // veh blocks in merged gat kernels
constexpr float LOFF = 4.0f;       // logit offset (cancels in softmax ratio)
constexpr int EPT = 4;             // edges per thread in CSR build pass-1

struct __align__(8) Edge { int s; __half2 ea; };
struct __align__(16) TRec { int s; int d; __half2 ea; int r; };
typedef __half2 h2;

__device__ __forceinline__ h2 h2shfl_xor(h2 v, int m) {
  int i = *(int*)&v;
  i = __shfl_xor(i, m);
  return *(h2*)&i;
}
__device__ __forceinline__ h2 h2max(h2 a, h2 b) {
  h2 r;
  asm("v_pk_max_f16 %0, %1, %2" : "=v"(r) : "v"(a), "v"(b));
  return r;
}

// ---------------- workspace layout (float units) ----------------
constexpr size_t OFF_CUR_VV = 0;                        // NV (zeroed)
constexpr size_t OFF_CUR_IV = OFF_CUR_VV + NV;          // NV (zeroed)
constexpr size_t OFF_CUR_VI = OFF_CUR_IV + NV;          // NR (zeroed)
constexpr size_t ZERO_END   = OFF_CUR_VI + NR;
constexpr size_t OFF_PTR_VV = ZERO_END;                 // NV+2
constexpr size_t OFF_PTR_IV = OFF_PTR_VV + NV + 2;
constexpr size_t OFF_PTR_VI = OFF_PTR_IV + NV + 2;
constexpr size_t OFF_E_VV   = (OFF_PTR_VI + NR + 2 + 3) & ~(size_t)3;
constexpr size_t OFF_E_IV   = OFF_E_VV + (size_t)EVV * 2;
constexpr size_t OFF_E_VI   = OFF_E_IV + (size_t)EIV * 2;
constexpr size_t OFF_TMP    = (OFF_E_VI + (size_t)EVI * 2 + 3) & ~(size_t)3;  // TRec = 4 floats
constexpr size_t OFF_H      = (OFF_TMP + (size_t)ETOT * 4 + 3) & ~(size_t)3;
// layer-1 tables: 128 halves/row = 64 float-units/row (head-interleaved: pos p = c*2+h)
constexpr size_t OFF_HL_VV1 = OFF_H;
constexpr size_t OFF_HR_VV1 = OFF_HL_VV1 + (size_t)NV * 64;
constexpr size_t OFF_HR_IV1 = OFF_HR_VV1 + (size_t)NV * 64;
constexpr size_t OFF_HL_VI1 = OFF_HR_IV1 + (size_t)NV * 64;
constexpr size_t OFF_HL_IV1 = OFF_HL_VI1 + (size_t)NV * 64;
constexpr size_t OFF_HR_VI1 = OFF_HL_IV1 + (size_t)NR * 64;
constexpr size_t L1_END     = OFF_HR_VI1 + (size_t)NR * 64;
// v1/r1: fp16 standard channel order (128 halves/row)
constexpr size_t OFF_V1     = L1_END;
constexpr size_t OFF_R1     = OFF_V1 + (size_t)NV * 64;
constexpr size_t WS_END     = OFF_R1 + (size_t)NR * 64;
// layer-2 tables overlay layer-1 region: 64 halves/row (standard order)
constexpr size_t OFF_HL_VV2 = OFF_H;
constexpr size_t OFF_HR_VV2 = OFF_HL_VV2 + (size_t)NV * 32;
constexpr size_t OFF_HR_IV2 = OFF_HR_VV2 + (size_t)NV * 32;
constexpr size_t OFF_HL_VI2 = OFF_HR_IV2 + (size_t)NV * 32;
constexpr size_t OFF_HL_IV2 = OFF_HL_VI2 + (size_t)NV * 32;
constexpr size_t OFF_HR_VI2 = OFF_HL_IV2 + (size_t)NR * 32;
constexpr size_t L2_END     = OFF_HR_VI2 + (size_t)NR * 32;
static_assert(L2_END <= OFF_V1, "layer-2 overlay must not clobber v1/r1");

// ---------------- combined layer-1 GEMM body ----------------
template<int K, int NW>
__device__ __forceinline__ void gemm1_body(float* xs, int bid,
    const float* __restrict__ X,
    const float* __restrict__ W0, const float* __restrict__ W1,
    const float* __restrict__ W2, const float* __restrict__ W3,
    __half* __restrict__ Y0, __half* __restrict__ Y1,
    __half* __restrict__ Y2, __half* __restrict__ Y3, int n) {
  constexpr int ROWS = 8;
  int r0 = bid * ROWS;
  int tid = threadIdx.x;
  int col = tid & 127, grp = tid >> 7;
  for (int i = tid; i < ROWS * K; i += 256) {
    int gi = r0 * K + i;
    xs[i] = (gi < n * K) ? X[gi] : 0.f;
  }
  __syncthreads();
  int oidx = ((col & 63) << 1) + (col >> 6);
#pragma unroll
  for (int rep = 0; rep < NW / 2; rep++) {
    int wi = grp + rep * 2;
    const float* __restrict__ W = wi == 0 ? W0 : wi == 1 ? W1 : wi == 2 ? W2 : W3;
    __half* __restrict__ Y = wi == 0 ? Y0 : wi == 1 ? Y1 : wi == 2 ? Y2 : Y3;
    float acc[ROWS];
#pragma unroll
    for (int r = 0; r < ROWS; r++) acc[r] = 0.f;
#pragma unroll
    for (int k4 = 0; k4 < K / 4; k4++) {
      float w0 = W[(4 * k4 + 0) * 128 + col];
      float w1 = W[(4 * k4 + 1) * 128 + col];
      float w2 = W[(4 * k4 + 2) * 128 + col];
      float w3 = W[(4 * k4 + 3) * 128 + col];
#pragma unroll
      for (int r = 0; r < ROWS; r++) {
        float x0 = xs[r * K + 4 * k4], x1 = xs[r * K + 4 * k4 + 1];
        float x2 = xs[r * K + 4 * k4 + 2], x3 = xs[r * K + 4 * k4 + 3];
        acc[r] = fmaf(x0, w0, acc[r]);
        acc[r] = fmaf(x1, w1, acc[r]);
        acc[r] = fmaf(x2, w2, acc[r]);
        acc[r] = fmaf(x3, w3, acc[r]);
      }
    }
#pragma unroll
    for (int r = 0; r < ROWS; r++)
      if (r0 + r < n) Y[(size_t)(r0 + r) * 128 + oidx] = __float2half(acc[r]);
  }
}

// ---------------- fused CSR-build pass-1 (EPT edges/thread) + layer-1 GEMM ----------------
__global__ __launch_bounds__(256) void k_build1_gemm1(
    const int* __restrict__ svv, const int* __restrict__ dvv, const float* __restrict__ eavv,
    const int* __restrict__ siv, const int* __restrict__ div_, const float* __restrict__ eaiv,
    const int* __restrict__ svi, const int* __restrict__ dvi, const float* __restrict__ eavi,
    int* __restrict__ cvv, int* __restrict__ civ, int* __restrict__ cvi,
    TRec* __restrict__ tmp,
    const float* xv, const float* W0v, const float* W1v, const float* W2v, const float* W3v,
    __half* Y0v, __half* Y1v, __half* Y2v, __half* Y3v,
    const float* xr, const float* W0r, const float* W1r,
    __half* Y0r, __half* Y1r,
    int nb_build, int nbv) {
  __shared__ float xs[8 * 16];
  int bid = blockIdx.x;
  if (bid < nb_build) {
    int base = bid * (256 * EPT) + threadIdx.x;
#pragma unroll
    for (int k = 0; k < EPT; k++) {
      int t = base + k * 256;
      if (t < EVV) {
        int d = dvv[t];
        float2 ea = *(const float2*)&eavv[2 * t];
        TRec rec; rec.s = svv[t]; rec.d = d;
        rec.ea = __floats2half2_rn(ea.x, ea.y);
        rec.r = atomicAdd(&cvv[d], 1);
        tmp[t] = rec;
      } else if (t < EVV + EIV) {
        int e = t - EVV, d = div_[e];
        float2 ea = *(const float2*)&eaiv[2 * e];
        TRec rec; rec.s = siv[e]; rec.d = d;
        rec.ea = __floats2half2_rn(ea.x, ea.y);
        rec.r = atomicAdd(&civ[d], 1);
        tmp[t] = rec;
      } else if (t < ETOT) {
        int e = t - EVV - EIV, d = dvi[e];
        float2 ea = *(const float2*)&eavi[2 * e];
        TRec rec; rec.s = svi[e]; rec.d = d;
        rec.ea = __floats2half2_rn(ea.x, ea.y);
        rec.r = atomicAdd(&cvi[d], 1);
        tmp[t] = rec;
      }
    }
  } else if (bid < nb_build + nbv) {
    gemm1_body<16, 4>(xs, bid - nb_build, xv, W0v, W1v, W2v, W3v, Y0v, Y1v, Y2v, Y3v, NV);
  } else {
    gemm1_body<8, 2>(xs, bid - nb_build - nbv, xr, W0r, W1r, nullptr, nullptr,
                     Y0r, Y1r, nullptr, nullptr, NR);
  }
}

__global__ __launch_bounds__(1024) void k_scan3(
    const int* c0, int* p0, int n0,
    const int* c1, int* p1, int n1,
    const int* c2, int* p2, int n2) {
  const int* cnt = blockIdx.x == 0 ? c0 : blockIdx.x == 1 ? c1 : c2;
  int* ptr = blockIdx.x == 0 ? p0 : blockIdx.x == 1 ? p1 : p2;
  int n = blockIdx.x == 0 ? n0 : blockIdx.x == 1 ? n1 : n2;
  __shared__ int tsum[1024];
  int t = threadIdx.x;
  int per = (n + 1023) >> 10;
  int base = t * per;
  int s = 0;
  for (int i = 0; i < per; i++) { int idx = base + i; if (idx < n) s += cnt[idx]; }
  tsum[t] = s;
  for (int off = 1; off < 1024; off <<= 1) {
    __syncthreads();
    int v = (t >= off) ? tsum[t - off] : 0;
    __syncthreads();
    tsum[t] += v;
  }
  __syncthreads();
  int run = tsum[t] - s;
  for (int i = 0; i < per; i++) {
    int idx = base + i;
    if (idx < n) { ptr[idx] = run; run += cnt[idx]; }
  }
  if (t == 1023) ptr[n] = tsum[1023];
}

__global__ __launch_bounds__(256) void k_build2(
    const TRec* __restrict__ tmp,
    const int* __restrict__ pvv, const int* __restrict__ piv, const int* __restrict__ pvi,
    Edge* __restrict__ evv, Edge* __restrict__ eiv, Edge* __restrict__ evi) {
  int t = blockIdx.x * blockDim.x + threadIdx.x;
  if (t >= ETOT) return;
  TRec rec = tmp[t];
  Edge ed; ed.s = rec.s; ed.ea = rec.ea;
  if (t < EVV)            evv[pvv[rec.d] + rec.r] = ed;
  else if (t < EVV + EIV) eiv[piv[rec.d] + rec.r] = ed;
  else                    evi[pvi[rec.d] + rec.r] = ed;
}

// ---------------- combined layer-2 GEMM (veh + rsu in one launch) ----------------
template<int NW>
__device__ __forceinline__ void gemm2_body(float* xs, int bid,
    const __half* __restrict__ X,
    const float* __restrict__ W0, const float* __restrict__ W1,
    const float* __restrict__ W2, const float* __restrict__ W3,
    __half* __restrict__ Y0, __half* __restrict__ Y1,
    __half* __restrict__ Y2, __half* __restrict__ Y3, int n) {
  constexpr int ROWS = 16, K = 128;
  int r0 = bid * ROWS;
  int tid = threadIdx.x;
  const __half2* X2 = (const __half2*)X;
  for (int i = tid; i < ROWS * K / 2; i += 256) {
    int gi = r0 * (K / 2) + i;
    float2 f = (gi < n * (K / 2)) ? __half22float2(X2[gi]) : make_float2(0.f, 0.f);
    xs[2 * i] = f.x;
    xs[2 * i + 1] = f.y;
  }
  __syncthreads();
  int lane = tid & 63, wv = tid >> 6;
  if (wv >= NW) return;
  const float* __restrict__ W = wv == 0 ? W0 : wv == 1 ? W1 : wv == 2 ? W2 : W3;
  __half* __restrict__ Y = wv == 0 ? Y0 : wv == 1 ? Y1 : wv == 2 ? Y2 : Y3;
  float acc[ROWS];
#pragma unroll
  for (int r = 0; r < ROWS; r++) acc[r] = 0.f;
  for (int k4 = 0; k4 < K / 4; k4++) {
    float w0 = W[(4 * k4 + 0) * 64 + lane];
    float w1 = W[(4 * k4 + 1) * 64 + lane];
    float w2 = W[(4 * k4 + 2) * 64 + lane];
    float w3 = W[(4 * k4 + 3) * 64 + lane];
#pragma unroll
    for (int r = 0; r < ROWS; r++) {
      float x0 = xs[r * K + 4 * k4], x1 = xs[r * K + 4 * k4 + 1];
      float x2 = xs[r * K + 4 * k4 + 2], x3 = xs[r * K + 4 * k4 + 3];
      acc[r] = fmaf(x0, w0, acc[r]);
      acc[r] = fmaf(x1, w1, acc[r]);
      acc[r] = fmaf(x2, w2, acc[r]);
      acc[r] = fmaf(x3, w3, acc[r]);
    }
  }
#pragma unroll
  for (int r = 0; r < ROWS; r++)
    if (r0 + r < n) Y[(size_t)(r0 + r) * 64 + lane] = __float2half(acc[r]);
}

__global__ __launch_bounds__(256) void k_gemm2c(
    const __half* xv, const float* W0v, const float* W1v, const float* W2v, const float* W3v,
    __half* Y0v, __half* Y1v, __half* Y2v, __half* Y3v,
    const __half* xr, const float* W0r, const float* W1r,
    __half* Y0r, __half* Y1r, int nbv) {
  __shared__ float xs[16 * 128];
  if ((int)blockIdx.x < nbv)
    gemm2_body<4>(xs, blockIdx.x, xv, W0v, W1v, W2v, W3v, Y0v, Y1v, Y2v, Y3v, NV);
  else
    gemm2_body<2>(xs, blockIdx.x - nbv, xr, W0r, W1r, nullptr, nullptr,
                  Y0r, Y1r, nullptr, nullptr, NR);
}

// ---------------- window-preloaded GATv2 (pk-fp16; window0 + hr preloaded by caller) ----------------

// layer-1: H=2, head-interleaved rows, 16-lane groups; 16-chunk + 4-stride tail
template<bool SELF>
__device__ __forceinline__ void gatW2(int d, int lane, int eg, int cg,
    int b, int cnt, int es0, int eab0,
    const Edge* __restrict__ ed,
    const __half* __restrict__ hl, float4 hrr,
    const float* __restrict__ We, const float* __restrict__ att,
    float* acc, float& den0, float& den1) {
  h2 hrc2[4], av2[4], w02[4], w12[4];
  const h2* hrp = (const h2*)&hrr;
#pragma unroll
  for (int j = 0; j < 4; j++) hrc2[j] = hrp[j];
#pragma unroll
  for (int j = 0; j < 4; j++) {
    int c = cg * 4 + j;
    av2[j] = __floats2half2_rn(att[c], att[64 + c]);
    w02[j] = __floats2half2_rn(We[c], We[64 + c]);
    w12[j] = __floats2half2_rn(We[128 + c], We[192 + c]);
  }
  const h2 c02 = __float2half2_rn(0.2f);
  h2 acc2[4];
#pragma unroll
  for (int j = 0; j < 4; j++) acc2[j] = __float2half2_rn(0.f);
  float sum0 = 0.f, sum1 = 0.f;
  auto proc = [&](float4 r, int eab, bool v) {
    const h2* hp = (const h2*)&r;
    h2 eh = *(h2*)&eab;
    h2 ef0 = __low2half2(eh), ef1 = __high2half2(eh);
    h2 lacc = __float2half2_rn(0.f);
#pragma unroll
    for (int j = 0; j < 4; j++) {
      h2 g = __hfma2(ef0, w02[j], __hadd2(hp[j], hrc2[j]));
      g = __hfma2(ef1, w12[j], g);
      h2 lr = h2max(g, __hmul2(c02, g));
      lacc = __hfma2(lr, av2[j], lacc);
    }
#pragma unroll
    for (int o = 1; o <= 8; o <<= 1) lacc = __hadd2(lacc, h2shfl_xor(lacc, o));
    float2 lf = __half22float2(lacc);
    float ex0 = v ? __expf(lf.x - LOFF) : 0.f;
    float ex1 = v ? __expf(lf.y - LOFF) : 0.f;
    h2 exh = __floats2half2_rn(ex0, ex1);
#pragma unroll
    for (int j = 0; j < 4; j++) acc2[j] = __hfma2(exh, hp[j], acc2[j]);
    den0 += ex0; den1 += ex1;
  };
  auto doWin = [&](int es, int eab, int wlen) {
    int kk = 0;
    for (; kk + 16 <= wlen; kk += 16) {
      int k0 = kk + eg, k1 = kk + 4 + eg, k2 = kk + 8 + eg, k3 = kk + 12 + eg;
      int s0 = __shfl(es, k0), ea0 = __shfl(eab, k0);
      int s1 = __shfl(es, k1), ea1 = __shfl(eab, k1);
      int s2 = __shfl(es, k2), ea2 = __shfl(eab, k2);
      int s3 = __shfl(es, k3), ea3 = __shfl(eab, k3);
      float4 r0 = *(const float4*)&hl[(size_t)s0 * 128 + cg * 8];
      float4 r1 = *(const float4*)&hl[(size_t)s1 * 128 + cg * 8];
      float4 r2 = *(const float4*)&hl[(size_t)s2 * 128 + cg * 8];
      float4 r3 = *(const float4*)&hl[(size_t)s3 * 128 + cg * 8];
      proc(r0, ea0, true);
      proc(r1, ea1, true);
      proc(r2, ea2, true);
      proc(r3, ea3, true);
    }
    for (; kk < wlen; kk += 4) {
      int k0 = kk + eg;
      int s0 = __shfl(es, k0), ea0 = __shfl(eab, k0);
      float4 r0 = *(const float4*)&hl[(size_t)s0 * 128 + cg * 8];
      proc(r0, ea0, k0 < wlen);
    }
  };
  if (SELF) {
    float2 f = __half22float2(*(h2*)&eab0);
    sum0 += f.x; sum1 += f.y;
  }
  doWin(es0, eab0, min(64, cnt));
  for (int wf = 64; wf < cnt; wf += 64) {
    int idx = wf + lane;
    int es = 0, eab = 0;
    if (idx < cnt) { Edge e = ed[b + idx]; es = e.s; eab = *(const int*)&e.ea; }
    if (SELF) {
      float2 f = __half22float2(*(h2*)&eab);
      sum0 += f.x; sum1 += f.y;
    }
    doWin(es, eab, min(64, cnt - wf));
  }
  if (SELF) {
#pragma unroll
    for (int o = 1; o <= 32; o <<= 1) { sum0 += __shfl_xor(sum0, o); sum1 += __shfl_xor(sum1, o); }
    float dg = fmaxf((float)cnt, 1.f);
    __half2 mh = __floats2half2_rn(sum0 / dg, sum1 / dg);
    int meab = *(const int*)&mh;
    float4 rS = *(const float4*)&hl[(size_t)d * 128 + cg * 8];
    proc(rS, meab, eg == 0);
  }
#pragma unroll
  for (int o = 16; o <= 32; o <<= 1) {
#pragma unroll
    for (int j = 0; j < 4; j++) acc2[j] = __hadd2(acc2[j], h2shfl_xor(acc2[j], o));
    den0 += __shfl_xor(den0, o);
    den1 += __shfl_xor(den1, o);
  }
#pragma unroll
  for (int j = 0; j < 4; j++) {
    float2 f = __half22float2(acc2[j]);
    acc[2 * j] = f.x; acc[2 * j + 1] = f.y;
  }
}

// layer-2: H=1, standard rows, 8-lane groups; 32-chunk + 8-stride tail
template<bool SELF>
__device__ __forceinline__ void gatW1(int d, int lane, int eg8, int cg8,
    int b, int cnt, int es0, int eab0,
    const Edge* __restrict__ ed,
    const __half* __restrict__ hl, float4 hrr,
    const float* __restrict__ We, const float* __restrict__ att,
    float* acc, float& den) {
  h2 hrc2[4], av2[4], w02[4], w12[4];
  const h2* hrp = (const h2*)&hrr;
#pragma unroll
  for (int j = 0; j < 4; j++) hrc2[j] = hrp[j];
#pragma unroll
  for (int j = 0; j < 4; j++) {
    int c = cg8 * 8 + 2 * j;
    av2[j] = __floats2half2_rn(att[c], att[c + 1]);
    w02[j] = __floats2half2_rn(We[c], We[c + 1]);
    w12[j] = __floats2half2_rn(We[64 + c], We[64 + c + 1]);
  }
  const h2 c02 = __float2half2_rn(0.2f);
  h2 acc2[4];
#pragma unroll
  for (int j = 0; j < 4; j++) acc2[j] = __float2half2_rn(0.f);
  float sum0 = 0.f, sum1 = 0.f;
  auto proc = [&](float4 r, int eab, bool v) {
    const h2* hp = (const h2*)&r;
    h2 eh = *(h2*)&eab;
    h2 ef0 = __low2half2(eh), ef1 = __high2half2(eh);
    h2 lacc = __float2half2_rn(0.f);
#pragma unroll
    for (int j = 0; j < 4; j++) {
      h2 g = __hfma2(ef0, w02[j], __hadd2(hp[j], hrc2[j]));
      g = __hfma2(ef1, w12[j], g);
      h2 lr = h2max(g, __hmul2(c02, g));
      lacc = __hfma2(lr, av2[j], lacc);
    }
#pragma unroll
    for (int o = 1; o <= 4; o <<= 1) lacc = __hadd2(lacc, h2shfl_xor(lacc, o));
    float2 lf = __half22float2(lacc);
    float ex = v ? __expf(lf.x + lf.y - LOFF) : 0.f;
    h2 exh = __float2half2_rn(ex);
#pragma unroll
    for (int j = 0; j < 4; j++) acc2[j] = __hfma2(exh, hp[j], acc2[j]);
    den += ex;
  };
  auto doWin = [&](int es, int eab, int wlen) {
    int kk = 0;
    for (; kk + 32 <= wlen; kk += 32) {
      int k0 = kk + eg8, k1 = kk + 8 + eg8, k2 = kk + 16 + eg8, k3 = kk + 24 + eg8;
      int s0 = __shfl(es, k0), ea0 = __shfl(eab, k0);
      int s1 = __shfl(es, k1), ea1 = __shfl(eab, k1);
      int s2 = __shfl(es, k2), ea2 = __shfl(eab, k2);
      int s3 = __shfl(es, k3), ea3 = __shfl(eab, k3);
      float4 r0 = *(const float4*)&hl[(size_t)s0 * 64 + cg8 * 8];
      float4 r1 = *(const float4*)&hl[(size_t)s1 * 64 + cg8 * 8];
      float4 r2 = *(const float4*)&hl[(size_t)s2 * 64 + cg8 * 8];
      float4 r3 = *(const float4*)&hl[(size_t)s3 * 64 + cg8 * 8];
      proc(r0, ea0, true);
      proc(r1, ea1, true);
      proc(r2, ea2, true);
      proc(r3, ea3, true);
    }
    for (; kk < wlen; kk += 8) {
      int k0 = kk + eg8;
      int s0 = __shfl(es, k0), ea0 = __shfl(eab, k0);
      float4 r0 = *(const float4*)&hl[(size_t)s0 * 64 + cg8 * 8];
      proc(r0, ea0, k0 < wlen);
    }
  };
  if (SELF) {
    float2 f = __half22float2(*(h2*)&eab0);
    sum0 += f.x; sum1 += f.y;
  }
  doWin(es0, eab0, min(64, cnt));
  for (int wf = 64; wf < cnt; wf += 64) {
    int idx = wf + lane;
    int es = 0, eab = 0;
    if (idx < cnt) { Edge e = ed[b + idx]; es = e.s; eab = *(const int*)&e.ea; }
    if (SELF) {
      float2 f = __half22float2(*(h2*)&eab);
      sum0 += f.x; sum1 += f.y;
    }
    doWin(es, eab, min(64, cnt - wf));
  }
  if (SELF) {
#pragma unroll
    for (int o = 1; o <= 32; o <<= 1) { sum0 += __shfl_xor(sum0, o); sum1 += __shfl_xor(sum1, o); }
    float dg = fmaxf((float)cnt, 1.f);
    __half2 mh = __floats2half2_rn(sum0 / dg, sum1 / dg);
    int meab = *(const int*)&mh;
    float4 rS = *(const float4*)&hl[(size_t)d * 64 + cg8 * 8];
    proc(rS, meab, eg8 == 0);
  }
#pragma unroll
  for (int o = 8; o <= 32; o <<= 1) {
#pragma unroll
    for (int j = 0; j < 4; j++) acc2[j] = __hadd2(acc2[j], h2shfl_xor(acc2[j], o));
    den += __shfl_xor(den, o);
  }
#pragma unroll
  for (int j = 0; j < 4; j++) {
    float2 f = __half22float2(acc2[j]);
    acc[2 * j] = f.x; acc[2 * j + 1] = f.y;
  }
}

// layer-1 merged: blocks [0,NR) = rsu (block/dst), [NR,NR+VB) = veh (wave/dst)
__global__ __launch_bounds__(256) void k_gat_l1(
    const int* ptr_vv, const Edge* e_vv,
    const __half* hl_vv, const __half* hr_vv, const float* We_vv, const float* att_vv,
    const int* ptr_iv, const Edge* e_iv,
    const __half* hl_iv, const __half* hr_iv, const float* We_iv, const float* att_iv,
    const int* ptr_vi, const Edge* e_vi,
    const __half* hl_vi, const __half* hr_vi, const float* We_vi, const float* att_vi,
    const float* b_vv, const float* b_iv, const float* b_vi,
    __half* __restrict__ v1, __half* __restrict__ r1) {
  __shared__ float sm[4][16][10];
  int lane = threadIdx.x & 63, wv = threadIdx.x >> 6;
  int eg = lane >> 4, cg = lane & 15;
  if (blockIdx.x >= NR) {
    int w = (blockIdx.x - NR) * 4 + wv;
    if (w >= NV) return;
    int b1 = ptr_vv[w], c1 = ptr_vv[w + 1] - b1;
    int b2 = ptr_iv[w], c2 = ptr_iv[w + 1] - b2;
    int es1 = 0, ea1 = 0, es2 = 0, ea2 = 0;
    if (lane < c1) { Edge e = e_vv[b1 + lane]; es1 = e.s; ea1 = *(const int*)&e.ea; }
    if (lane < c2) { Edge e = e_iv[b2 + lane]; es2 = e.s; ea2 = *(const int*)&e.ea; }
    float4 hrv = *(const float4*)&hr_vv[(size_t)w * 128 + cg * 8];
    float4 hri = *(const float4*)&hr_iv[(size_t)w * 128 + cg * 8];
    float acc[8];
    float d0 = 0.f, d1 = 0.f, oc[8];
    gatW2<true>(w, lane, eg, cg, b1, c1, es1, ea1, e_vv, hl_vv, hrv, We_vv, att_vv, acc, d0, d1);
#pragma unroll
    for (int j = 0; j < 8; j++) oc[j] = acc[j] / (((j & 1) ? d1 : d0) + 1e-16f);
    d0 = d1 = 0.f;
    gatW2<false>(w, lane, eg, cg, b2, c2, es2, ea2, e_iv, hl_iv, hri, We_iv, att_iv, acc, d0, d1);
#pragma unroll
    for (int j = 0; j < 8; j++) oc[j] += acc[j] / (((j & 1) ? d1 : d0) + 1e-16f);
    if (eg == 0) {
      float x[8];
#pragma unroll
      for (int j = 0; j < 8; j++) {
        int c = cg * 4 + (j >> 1);
        int idx = (j & 1) * 64 + c;
        float v = oc[j] + b_vv[idx] + b_iv[idx];
        x[j] = v > 0.f ? v : __expf(v) - 1.f;
      }
      __half2 h0a = __floats2half2_rn(x[0], x[2]), h0b = __floats2half2_rn(x[4], x[6]);
      __half2 h1a = __floats2half2_rn(x[1], x[3]), h1b = __floats2half2_rn(x[5], x[7]);
      float2 p0, p1;
      ((__half2*)&p0)[0] = h0a; ((__half2*)&p0)[1] = h0b;
      ((__half2*)&p1)[0] = h1a; ((__half2*)&p1)[1] = h1b;
      *(float2*)&v1[(size_t)w * 128 + cg * 4]      = p0;
      *(float2*)&v1[(size_t)w * 128 + 64 + cg * 4] = p1;
    }
  } else {
    int dd = blockIdx.x;
    int bfull = ptr_vi[dd], cntf = ptr_vi[dd + 1] - bfull;
    int q = (cntf + 3) >> 2;
    int off = min(wv * q, cntf);
    int cnt = min(q, cntf - off);
    int b = bfull + off;
    int es0 = 0, ea0 = 0;
    if (lane < cnt) { Edge e = e_vi[b + lane]; es0 = e.s; ea0 = *(const int*)&e.ea; }
    float4 hrr = *(const float4*)&hr_vi[(size_t)dd * 128 + cg * 8];
    float acc[8];
    float d0 = 0.f, d1 = 0.f;
    gatW2<false>(dd, lane, eg, cg, b, cnt, es0, ea0, e_vi, hl_vi, hrr, We_vi, att_vi, acc, d0, d1);
    if (eg == 0) {
#pragma unroll
      for (int j = 0; j < 8; j++) sm[wv][cg][j] = acc[j];
      sm[wv][cg][8] = d0; sm[wv][cg][9] = d1;
    }
    __syncthreads();
    if (wv == 0) {
#pragma unroll
      for (int j = 0; j < 8; j++)
        acc[j] = sm[0][cg][j] + sm[1][cg][j] + sm[2][cg][j] + sm[3][cg][j];
      d0 = sm[0][cg][8] + sm[1][cg][8] + sm[2][cg][8] + sm[3][cg][8];
      d1 = sm[0][cg][9] + sm[1][cg][9] + sm[2][cg][9] + sm[3][cg][9];
      if (eg == 0) {
        float x[8];
#pragma unroll
        for (int j = 0; j < 8; j++) {
          int c = cg * 4 + (j >> 1);
          int idx = (j & 1) * 64 + c;
          float v = acc[j] / (((j & 1) ? d1 : d0) + 1e-16f) + b_vi[idx];
          x[j] = v > 0.f ? v : __expf(v) - 1.f;
        }
        __half2 h0a = __floats2half2_rn(x[0], x[2]), h0b = __floats2half2_rn(x[4], x[6]);
        __half2 h1a = __floats2half2_rn(x[1], x[3]), h1b = __floats2half2_rn(x[5], x[7]);
        float2 p0, p1;
        ((__half2*)&p0)[0] = h0a; ((__half2*)&p0)[1] = h0b;
        ((__half2*)&p1)[0] = h1a; ((__half2*)&p1)[1] = h1b;
        *(float2*)&r1[(size_t)dd * 128 + cg * 4]      = p0;
        *(float2*)&r1[(size_t)dd * 128 + 64 + cg * 4] = p1;
      }
    }
  }
}

// layer-2 merged: rsu blocks first; veh rows -> out[0..NV), rsu -> out[NV..)
__global__ __launch_bounds__(256) void k_gat_l2(
    const int* ptr_vv, const Edge* e_vv,
    const __half* hl_vv, const __half* hr_vv, const float* We_vv, const float* att_vv,
    const int* ptr_iv, const Edge* e_iv,
    const __half* hl_iv, const __half* hr_iv, const float* We_iv, const float* att_iv,
    const int* ptr_vi, const Edge* e_vi,
    const __half* hl_vi, const __half* hr_vi, const float* We_vi, const float* att_vi,
    const float* b_vv, const float* b_iv, const float* b_vi,
    const float* ln_vg, const float* ln_vb, const float* ln_rg, const float* ln_rb,
    float* __restrict__ out) {
  __shared__ float sm[4][8][9];
  int lane = threadIdx.x & 63, wv = threadIdx.x >> 6;
  int eg8 = lane >> 3, cg8 = lane & 7;
  if (blockIdx.x >= NR) {
    int w = (blockIdx.x - NR) * 4 + wv;
    if (w >= NV) return;
    int b1 = ptr_vv[w], c1 = ptr_vv[w + 1] - b1;
    int b2 = ptr_iv[w], c2 = ptr_iv[w + 1] - b2;
    int es1 = 0, ea1 = 0, es2 = 0, ea2 = 0;
    if (lane < c1) { Edge e = e_vv[b1 + lane]; es1 = e.s; ea1 = *(const int*)&e.ea; }
    if (lane < c2) { Edge e = e_iv[b2 + lane]; es2 = e.s; ea2 = *(const int*)&e.ea; }
    float4 hrv = *(const float4*)&hr_vv[(size_t)w * 64 + cg8 * 8];
    float4 hri = *(const float4*)&hr_iv[(size_t)w * 64 + cg8 * 8];
    float acc[8];
    float dn = 0.f, oc[8];
    gatW1<true>(w, lane, eg8, cg8, b1, c1, es1, ea1, e_vv, hl_vv, hrv, We_vv, att_vv, acc, dn);
#pragma unroll
    for (int j = 0; j < 8; j++) oc[j] = acc[j] / (dn + 1e-16f);
    dn = 0.f;
    gatW1<false>(w, lane, eg8, cg8, b2, c2, es2, ea2, e_iv, hl_iv, hri, We_iv, att_iv, acc, dn);
    float x[8], s = 0.f;
#pragma unroll
    for (int j = 0; j < 8; j++) {
      int c = cg8 * 8 + j;
      x[j] = oc[j] + acc[j] / (dn + 1e-16f) + b_vv[c] + b_iv[c];
      s += x[j];
    }
#pragma unroll
    for (int o = 1; o <= 4; o <<= 1) s += __shfl_xor(s, o);
    float mu = s * (1.f / 64.f);
    float v = 0.f;
#pragma unroll
    for (int j = 0; j < 8; j++) { float dx = x[j] - mu; v = fmaf(dx, dx, v); }
#pragma unroll
    for (int o = 1; o <= 4; o <<= 1) v += __shfl_xor(v, o);
    float rstd = rsqrtf(v * (1.f / 64.f) + 1e-5f);
    if (eg8 == 0) {
      float4 o0, o1;
      float* ov = (float*)&o0;
#pragma unroll
      for (int j = 0; j < 4; j++) {
        int c = cg8 * 8 + j;
        ov[j] = (x[j] - mu) * rstd * ln_vg[c] + ln_vb[c];
      }
      ov = (float*)&o1;
#pragma unroll
      for (int j = 0; j < 4; j++) {
        int c = cg8 * 8 + 4 + j;
        ov[j] = (x[4 + j] - mu) * rstd * ln_vg[c] + ln_vb[c];
      }
      *(float4*)&out[(size_t)w * 64 + cg8 * 8]     = o0;
      *(float4*)&out[(size_t)w * 64 + cg8 * 8 + 4] = o1;
    }
  } else {
    int dd = blockIdx.x;
    int bfull = ptr_vi[dd], cntf = ptr_vi[dd + 1] - bfull;
    int q = (cntf + 3) >> 2;
    int off = min(wv * q, cntf);
    int cnt = min(q, cntf - off);
    int b = bfull + off;
    int es0 = 0, ea0 = 0;
    if (lane < cnt) { Edge e = e_vi[b + lane]; es0 = e.s; ea0 = *(const int*)&e.ea; }
    float4 hrr = *(const float4*)&hr_vi[(size_t)dd * 64 + cg8 * 8];
    float acc[8];
    float dn = 0.f;
    gatW1<false>(dd, lane, eg8, cg8, b, cnt, es0, ea0, e_vi, hl_vi, hrr, We_vi, att_vi, acc, dn);
    if (eg8 == 0) {
#pragma unroll
      for (int j = 0; j < 8; j++) sm[wv][cg8][j] = acc[j];
      sm[wv][cg8][8] = dn;
    }
    __syncthreads();
    if (wv == 0) {
#pragma unroll
      for (int j = 0; j < 8; j++)
        acc[j] = sm[0][cg8][j] + sm[1][cg8][j] + sm[2][cg8][j] + sm[3][cg8][j];
      dn = sm[0][cg8][8] + sm[1][cg8][8] + sm[2][cg8][8] + sm[3][cg8][8];
      float x[8], s = 0.f;
#pragma unroll
      for (int j = 0; j < 8; j++) {
        int c = cg8 * 8 + j;
        x[j] = acc[j] / (dn + 1e-16f) + b_vi[c];
        s += x[j];
      }
#pragma unroll
      for (int o = 1; o <= 4; o <<= 1) s += __shfl_xor(s, o);
      float mu = s * (1.f / 64.f);
      float v = 0.f;
#pragma unroll
      for (int j = 0; j < 8; j++) { float dx = x[j] - mu; v = fmaf(dx, dx, v); }
#pragma unroll
      for (int o = 1; o <= 4; o <<= 1) v += __shfl_xor(v, o);
      float rstd = rsqrtf(v * (1.f / 64.f) + 1e-5f);
      if (eg8 == 0) {
#pragma unroll
        for (int j = 0; j < 8; j++) {
          int c = cg8 * 8 + j;
          out[(size_t)(NV + dd) * 64 + c] = (x[j] - mu) * rstd * ln_rg[c] + ln_rb[c];
        }
      }
    }
  }
}

// ---------------- launch ----------------
extern "C" void kernel_launch(void* const* d_in, const int* in_sizes, int n_in,
                              void* d_out, int out_size, void* d_ws, size_t ws_size,
                              hipStream_t stream) {
  const float* x_veh  = (const float*)d_in[0];
  const float* x_rsu  = (const float*)d_in[1];
  const float* ea_vv  = (const float*)d_in[2];
  const float* ea_vi  = (const float*)d_in[3];
  const float* ea_iv  = (const float*)d_in[4];
  const int*   src_vv = (const int*)d_in[5];
  const int*   dst_vv = (const int*)d_in[6];
  const int*   src_vi = (const int*)d_in[7];
  const int*   dst_vi = (const int*)d_in[8];
  const int*   src_iv = (const int*)d_in[9];
  const int*   dst_iv = (const int*)d_in[10];
  const float* Wl_vv1 = (const float*)d_in[11];
  const float* Wr_vv1 = (const float*)d_in[12];
  const float* We_vv1 = (const float*)d_in[13];
  const float* att_vv1= (const float*)d_in[14];
  const float* b_vv1  = (const float*)d_in[15];
  const float* Wl_vi1 = (const float*)d_in[16];
  const float* Wr_vi1 = (const float*)d_in[17];
  const float* We_vi1 = (const float*)d_in[18];
  const float* att_vi1= (const float*)d_in[19];
  const float* b_vi1  = (const float*)d_in[20];
  const float* Wl_iv1 = (const float*)d_in[21];
  const float* Wr_iv1 = (const float*)d_in[22];
  const float* We_iv1 = (const float*)d_in[23];
  const float* att_iv1= (const float*)d_in[24];
  const float* b_iv1  = (const float*)d_in[25];
  const float* Wl_vv2 = (const float*)d_in[26];
  const float* Wr_vv2 = (const float*)d_in[27];
  const float* We_vv2 = (const float*)d_in[28];
  const float* att_vv2= (const float*)d_in[29];
  const float* b_vv2  = (const float*)d_in[30];
  const float* Wl_vi2 = (const float*)d_in[31];
  const float* Wr_vi2 = (const float*)d_in[32];
  const float* We_vi2 = (const float*)d_in[33];
  const float* att_vi2= (const float*)d_in[34];
  const float* b_vi2  = (const float*)d_in[35];
  const float* Wl_iv2 = (const float*)d_in[36];
  const float* Wr_iv2 = (const float*)d_in[37];
  const float* We_iv2 = (const float*)d_in[38];
  const float* att_iv2= (const float*)d_in[39];
  const float* b_iv2  = (const float*)d_in[40];
  const float* ln_vg  = (const float*)d_in[41];
  const float* ln_vb  = (const float*)d_in[42];
  const float* ln_rg  = (const float*)d_in[43];
  const float* ln_rb  = (const float*)d_in[44];

  float* ws  = (float*)d_ws;
  float* out = (float*)d_out;

  int* cur_vv = (int*)(ws + OFF_CUR_VV);
  int* cur_iv = (int*)(ws + OFF_CUR_IV);
  int* cur_vi = (int*)(ws + OFF_CUR_VI);
  int* ptr_vv = (int*)(ws + OFF_PTR_VV);
  int* ptr_iv = (int*)(ws + OFF_PTR_IV);
  int* ptr_vi = (int*)(ws + OFF_PTR_VI);
  Edge* e_vv = (Edge*)(ws + OFF_E_VV);
  Edge* e_iv = (Edge*)(ws + OFF_E_IV);
  Edge* e_vi = (Edge*)(ws + OFF_E_VI);
  TRec* tmp  = (TRec*)(ws + OFF_TMP);

  __half* hl_vv1 = (__half*)(ws + OFF_HL_VV1);
  __half* hr_vv1 = (__half*)(ws + OFF_HR_VV1);
  __half* hr_iv1 = (__half*)(ws + OFF_HR_IV1);
  __half* hl_vi1 = (__half*)(ws + OFF_HL_VI1);
  __half* hl_iv1 = (__half*)(ws + OFF_HL_IV1);
  __half* hr_vi1 = (__half*)(ws + OFF_HR_VI1);
  __half* v1 = (__half*)(ws + OFF_V1);
  __half* r1 = (__half*)(ws + OFF_R1);
  __half* hl_vv2 = (__half*)(ws + OFF_HL_VV2);
  __half* hr_vv2 = (__half*)(ws + OFF_HR_VV2);
  __half* hr_iv2 = (__half*)(ws + OFF_HR_IV2);
  __half* hl_vi2 = (__half*)(ws + OFF_HL_VI2);
  __half* hl_iv2 = (__half*)(ws + OFF_HL_IV2);
  __half* hr_vi2 = (__half*)(ws + OFF_HR_VI2);

  (void)hipMemsetAsync(ws, 0, ZERO_END * sizeof(float), stream);

  // fused: CSR build pass-1 (EPT edges/thread, blocks first) + layer-1 GEMM
  int nb_build = (ETOT + 256 * EPT - 1) / (256 * EPT);
  int nbv1 = (NV + 7) / 8, nbr1 = (NR + 7) / 8;
  k_build1_gemm1<<<nb_build + nbv1 + nbr1, 256, 0, stream>>>(
      src_vv, dst_vv, ea_vv, src_iv, dst_iv, ea_iv, src_vi, dst_vi, ea_vi,
      cur_vv, cur_iv, cur_vi, tmp,
      x_veh, Wl_vv1, Wr_vv1, Wr_iv1, Wl_vi1, hl_vv1, hr_vv1, hr_iv1, hl_vi1,
      x_rsu, Wl_iv1, Wr_vi1, hl_iv1, hr_vi1,
      nb_build, nbv1);

  k_scan3<<<3, 1024, 0, stream>>>(cur_vv, ptr_vv, NV, cur_iv, ptr_iv, NV, cur_vi, ptr_vi, NR);
  k_build2<<<(ETOT + 255) / 256, 256, 0, stream>>>(tmp, ptr_vv, ptr_iv, ptr_vi,
      e_vv, e_iv, e_vi);

  // layer-1 fused aggregation
  k_gat_l1<<<NR + VB, 256, 0, stream>>>(
      ptr_vv, e_vv, hl_vv1, hr_vv1, We_vv1, att_vv1,
      ptr_iv, e_iv, hl_iv1, hr_iv1, We_iv1, att_iv1,
      ptr_vi, e_vi, hl_vi1, hr_vi1, We_vi1, att_vi1,
      b_vv1, b_iv1, b_vi1, v1, r1);

  // layer-2 dense transforms (veh + rsu combined)
  int nbv2 = (NV + 15) / 16, nbr2 = (NR + 15) / 16;
  k_gemm2c<<<nbv2 + nbr2, 256, 0, stream>>>(v1,
      Wl_vv2, Wr_vv2, Wr_iv2, Wl_vi2, hl_vv2, hr_vv2, hr_iv2, hl_vi2,
      r1, Wl_iv2, Wr_vi2, hl_iv2, hr_vi2, nbv2);

  // layer-2 fused aggregation + LayerNorm -> out
  k_gat_l2<<<NR + VB, 256, 0, stream>>>(
      ptr_vv, e_vv, hl_vv2, hr_vv2, We_vv2, att_vv2,
      ptr_iv, e_iv, hl_iv2, hr_iv2, We_iv2, att_iv2,
      ptr_vi, e_vi, hl_vi2, hr_vi2, We_vi2, att_vi2,
      b_vv2, b_iv2, b_vi2, ln_vg, ln_vb, ln_rg, ln_rb, out);
  (void)in_sizes; (void)n_in; (void)out_size; (void)ws_size;
}